// Round 7
// baseline (2676.046 us; speedup 1.0000x reference)
//
#include <hip/hip_runtime.h>
#include <hip/hip_bf16.h>

// MambaEncoder on MI355X — v7: v5 structure, h-tile carried in REGISTERS
// (read h exactly once/layer -> nt streaming is now correct -> weight panels
// stay L2-resident), 3-deep B prefetch in waveB GEMMs, RMW in LN row layout.
// k_in_proj | k_layer x2 (block=sequence, 8 serial tiles, exact reg scan,
// 7 barriers/tile, As/Ss 32KB) | k_out. ws ~133.7MiB (proven).

typedef __attribute__((ext_vector_type(8))) __bf16 bf16x8;
typedef __attribute__((ext_vector_type(8))) short short8;
typedef __attribute__((ext_vector_type(4))) float f32x4;
typedef __attribute__((ext_vector_type(4))) unsigned u32x4;

#define NSEQ 512
#define KSEQ 512
#define FIN 96
#define DMODEL 256
#define MTOT (NSEQ*KSEQ)

__device__ __forceinline__ unsigned short f2bf(float f){
  union { float f; unsigned u; } v; v.f = f;
  unsigned r = (v.u + 0x7FFFu + ((v.u >> 16) & 1u)) >> 16;
  return (unsigned short)r;
}
__device__ __forceinline__ float bf2f(unsigned short b){
  union { unsigned u; float f; } v; v.u = ((unsigned)b) << 16; return v.f;
}
__device__ __forceinline__ unsigned pk_bf16(float lo, float hi){
  unsigned r;
  asm("v_cvt_pk_bf16_f32 %0, %1, %2" : "=v"(r) : "v"(lo), "v"(hi));
  return r;
}
__device__ __forceinline__ float gelu_f(float x){
  return 0.5f * x * (1.0f + erff(x * 0.70710678118654752440f));
}
__device__ __forceinline__ float silu_f(float x){
  return x / (1.0f + __expf(-x));
}
__device__ __forceinline__ unsigned swzA(int row, int kbyte){   // [64][256] bf16, 512B stride
  return ((unsigned)(row*512 + kbyte)) ^ (unsigned)((row & 7) << 4);
}
__device__ __forceinline__ unsigned swzB(int n, int kbyte){     // [256][64] bf16
  return ((unsigned)(n*128 + kbyte)) ^ (unsigned)((n & 7) << 4);
}

__device__ __forceinline__ void zero_acc(f32x4 (&acc)[4][4]){
  #pragma unroll
  for(int a=0;a<4;++a)
    #pragma unroll
    for(int b=0;b<4;++b)
      acc[a][b] = (f32x4){0.f,0.f,0.f,0.f};
}

// per-wave GEMM K=256: acc += A(64x256 bf16 LDS, swzA) @ W[256][256]^T.
// B direct from global (L2-resident) with 3-deep chunk prefetch (4-slot rot).
__device__ __forceinline__ void gemm_waveB(const unsigned short* __restrict__ wb,
                                           const char* As, f32x4 (&acc)[4][4],
                                           int lane, int c0)
{
  const int lr  = lane & 15;
  const int lk8 = (lane >> 4) * 8;
  const unsigned short* bp = wb + (size_t)(c0 + lr)*256 + lk8;   // + fc*4096 + kc*32
  bf16x8 bb[4][4];
  #pragma unroll
  for(int p = 0; p < 3; ++p)
    #pragma unroll
    for(int fc = 0; fc < 4; ++fc)
      bb[p][fc] = *(const bf16x8*)(bp + fc*4096 + p*32);
  #pragma unroll
  for(int kc = 0; kc < 8; ++kc){
    if(kc < 5){
      #pragma unroll
      for(int fc = 0; fc < 4; ++fc)
        bb[(kc+3)&3][fc] = *(const bf16x8*)(bp + fc*4096 + (kc+3)*32);
    }
    bf16x8 af[4];
    #pragma unroll
    for(int fr = 0; fr < 4; ++fr)
      af[fr] = *(const bf16x8*)(As + swzA(fr*16 + lr, kc*64 + lk8*2));
    #pragma unroll
    for(int fr = 0; fr < 4; ++fr)
      #pragma unroll
      for(int fc = 0; fc < 4; ++fc)
        acc[fr][fc] = __builtin_amdgcn_mfma_f32_16x16x32_bf16(af[fr], bb[kc&3][fc], acc[fr][fc], 0, 0, 0);
  }
}

// LDS-staged GEMM (k_in_proj / k_out only, proven)
template<int KCH>
__device__ __forceinline__ void gemm_64x256(const unsigned short* __restrict__ wb,
                                            char* As, char* Bs,
                                            f32x4 (&acc)[4][4], int tid)
{
  const int lane = tid & 63;
  const int c0   = (tid >> 6) * 64;
  const int lr   = lane & 15;
  const int lk16 = (lane >> 4) * 16;
  #pragma unroll
  for(int kc = 0; kc < KCH; ++kc){
    __syncthreads();
    {
      const unsigned short* src = wb + (size_t)tid * (KCH*64) + kc*64;
      #pragma unroll
      for(int i = 0; i < 8; ++i){
        short8 v = *(const short8*)(src + i*8);
        *(short8*)(Bs + swzB(tid, i*16)) = v;
      }
    }
    __syncthreads();
    #pragma unroll
    for(int t2 = 0; t2 < 2; ++t2){
      bf16x8 af[4], bfr[4];
      #pragma unroll
      for(int fr = 0; fr < 4; ++fr)
        af[fr] = *(const bf16x8*)(As + swzA(fr*16 + lr, kc*128 + t2*64 + lk16));
      #pragma unroll
      for(int fc = 0; fc < 4; ++fc)
        bfr[fc] = *(const bf16x8*)(Bs + swzB(c0 + fc*16 + lr, t2*64 + lk16));
      #pragma unroll
      for(int fr = 0; fr < 4; ++fr)
        #pragma unroll
        for(int fc = 0; fc < 4; ++fc)
          acc[fr][fc] = __builtin_amdgcn_mfma_f32_16x16x32_bf16(af[fr], bfr[fc], acc[fr][fc], 0, 0, 0);
    }
  }
}

// ---------------- prep kernels ----------------
__global__ void k_cvt(const float* __restrict__ s, unsigned short* __restrict__ d, int n){
  int i = blockIdx.x*256 + threadIdx.x;
  if(i < n) d[i] = f2bf(s[i]);
}
__global__ void k_cvt_inw(const float* __restrict__ w, unsigned short* __restrict__ d){
  int i = blockIdx.x*256 + threadIdx.x;
  int n = i >> 7, f = i & 127;
  d[i] = (f < 96) ? f2bf(w[n*96 + f]) : (unsigned short)0;
}
__global__ void k_spT(const float* __restrict__ spw, unsigned short* __restrict__ d){
  int l = blockIdx.y;
  int i = blockIdx.x*256 + threadIdx.x;
  int dd = i >> 8, ss = i & 255;
  d[l*65536 + i] = f2bf(spw[l*65536 + ss*256 + dd]);
}
__global__ void k_decay(const float* __restrict__ A_log, float* __restrict__ decay){
  __shared__ float red[4];
  const int b = blockIdx.x;            // l*256 + d
  const int tid = threadIdx.x;
  float v = expf(A_log[(size_t)b*256 + tid]);
  #pragma unroll
  for(int o = 32; o >= 1; o >>= 1) v += __shfl_xor(v, o);
  if((tid & 63) == 0) red[tid >> 6] = v;
  __syncthreads();
  if(tid == 0){
    float s = red[0] + red[1] + red[2] + red[3];
    decay[b] = expf(-s * (1.f/256.f));
  }
}

// ---------------- h = gelu(LN(x @ in_w^T + in_b)) -> bf16 ----------------
__global__ __launch_bounds__(256) void k_in_proj(
    const float* __restrict__ x_g,
    const unsigned short* __restrict__ in_wb,
    const float* __restrict__ in_b,
    const float* __restrict__ ln_gv, const float* __restrict__ ln_bv,
    unsigned short* __restrict__ h_g)
{
  __shared__ char smem[65536];
  char* As = smem; char* Bs = smem + 32768;
  const int tid = threadIdx.x;
  const int m0 = blockIdx.x * 64;
  const int lane = tid & 63, c0w = (tid>>6)*64, lr = lane & 15, rb = (lane>>4)*4;
  {
    const int r = tid >> 2, cq = tid & 3;
    const float* src = x_g + (size_t)(m0 + r)*FIN + cq*24;
    unsigned short tmp[24] __attribute__((aligned(16)));
    #pragma unroll
    for(int i = 0; i < 6; ++i){
      f32x4 v = __builtin_nontemporal_load((const f32x4*)(src + i*4));
      tmp[4*i]=f2bf(v[0]); tmp[4*i+1]=f2bf(v[1]); tmp[4*i+2]=f2bf(v[2]); tmp[4*i+3]=f2bf(v[3]);
    }
    #pragma unroll
    for(int i = 0; i < 3; ++i)
      *(short8*)(As + swzA(r, cq*48 + i*16)) = *(const short8*)(tmp + i*8);
    if(cq == 3){
      short8 z8 = {0,0,0,0,0,0,0,0};
      #pragma unroll
      for(int i = 0; i < 4; ++i)
        *(short8*)(As + swzA(r, 192 + i*16)) = z8;
    }
  }
  f32x4 acc[4][4]; zero_acc(acc);
  gemm_64x256<2>(in_wb, As, Bs, acc, tid);
  __syncthreads();
  #pragma unroll
  for(int fc = 0; fc < 4; ++fc){
    const int col = c0w + fc*16 + lr;
    const float bb = in_b[col];
    #pragma unroll
    for(int fr = 0; fr < 4; ++fr)
      #pragma unroll
      for(int rg = 0; rg < 4; ++rg){
        const int row = fr*16 + rb + rg;
        *(float*)(smem + (((unsigned)(row*1024 + col*4)) ^ ((row&7)<<4))) = acc[fr][fc][rg] + bb;
      }
  }
  __syncthreads();
  {
    const int r = tid >> 2, c0 = (tid & 3) * 64;
    float vals[64]; float sm = 0.f, sq = 0.f;
    #pragma unroll
    for(int i = 0; i < 16; ++i){
      float4 v = *(const float4*)(smem + (((unsigned)(r*1024 + (c0 + i*4)*4)) ^ ((r&7)<<4)));
      vals[4*i]=v.x; vals[4*i+1]=v.y; vals[4*i+2]=v.z; vals[4*i+3]=v.w;
    }
    #pragma unroll
    for(int i = 0; i < 64; ++i){ sm += vals[i]; sq += vals[i]*vals[i]; }
    sm += __shfl_xor(sm, 1); sm += __shfl_xor(sm, 2);
    sq += __shfl_xor(sq, 1); sq += __shfl_xor(sq, 2);
    const float mu = sm * (1.f/256.f);
    const float rstd = rsqrtf(sq * (1.f/256.f) - mu*mu + 1e-5f);
    unsigned short* dst = h_g + (size_t)(m0 + r)*DMODEL + c0;
    #pragma unroll
    for(int i = 0; i < 8; ++i){
      float g[8];
      #pragma unroll
      for(int j = 0; j < 8; ++j){
        const int c = c0 + i*8 + j;
        g[j] = gelu_f((vals[i*8+j]-mu)*rstd*ln_gv[c] + ln_bv[c]);
      }
      u32x4 o;
      o[0] = pk_bf16(g[0],g[1]); o[1] = pk_bf16(g[2],g[3]);
      o[2] = pk_bf16(g[4],g[5]); o[3] = pk_bf16(g[6],g[7]);
      __builtin_nontemporal_store(o, (u32x4*)(dst + i*8));
    }
  }
}

// ---------------- full layer: block = sequence, 8 serial tiles, exact scan ----------------
__global__ __launch_bounds__(256,2) void k_layer(
    unsigned short* __restrict__ h_g,
    const unsigned short* __restrict__ gate_wb,
    const unsigned short* __restrict__ sp_wb,
    const unsigned short* __restrict__ spT_wb,
    const unsigned short* __restrict__ op_wb,
    const float* __restrict__ ln_gv, const float* __restrict__ ln_bv,
    const float* __restrict__ gate_bv, const float* __restrict__ sp_bv,
    const float* __restrict__ decay_v, const float* __restrict__ D_v,
    const float* __restrict__ op_bv,
    float* __restrict__ state_buf, const int layer)
{
  __shared__ char As[32768];
  __shared__ char Ss[32768];
  const int tid = threadIdx.x;
  const int n = blockIdx.x;
  const int lane = tid & 63, c0w = (tid>>6)*64, lr = lane & 15, rb = (lane>>4)*4;
  const float dc = decay_v[tid];
  float st = (layer > 0) ? state_buf[n*256 + tid] : 0.f;
  const int rA = tid >> 2, cA = (tid & 3) * 64;     // per-lane LN row/col base

  // prefetch tile-0 h rows into registers (h read exactly once per layer)
  short8 hv[8];
  {
    const unsigned short* src = h_g + (size_t)(n*KSEQ + rA)*DMODEL + cA;
    #pragma unroll
    for(int i = 0; i < 8; ++i) hv[i] = __builtin_nontemporal_load((const short8*)(src + i*8));
  }

  #pragma unroll 1
  for(int kb = 0; kb < 8; ++kb){
    const int m0 = n*KSEQ + kb*64;
    // ---- Phase A: LN(hv regs) -> z bf16 in As ----
    {
      float sm = 0.f, sq = 0.f;
      #pragma unroll
      for(int i = 0; i < 8; ++i)
        #pragma unroll
        for(int j = 0; j < 8; ++j){
          float v = bf2f((unsigned short)hv[i][j]); sm += v; sq += v*v;
        }
      sm += __shfl_xor(sm, 1); sm += __shfl_xor(sm, 2);
      sq += __shfl_xor(sq, 1); sq += __shfl_xor(sq, 2);
      const float mu = sm * (1.f/256.f);
      const float rstd = rsqrtf(sq * (1.f/256.f) - mu*mu + 1e-5f);
      #pragma unroll
      for(int i = 0; i < 8; ++i){
        float z[8];
        #pragma unroll
        for(int j = 0; j < 8; ++j){
          const int c = cA + i*8 + j;
          z[j] = (bf2f((unsigned short)hv[i][j])-mu)*rstd*ln_gv[c] + ln_bv[c];
        }
        u32x4 zz;
        zz[0] = pk_bf16(z[0],z[1]); zz[1] = pk_bf16(z[2],z[3]);
        zz[2] = pk_bf16(z[4],z[5]); zz[3] = pk_bf16(z[6],z[7]);
        *(u32x4*)(As + swzA(rA, cA*2 + i*16)) = zz;
      }
    }
    __syncthreads();                                   // S1
    f32x4 acc[4][4]; zero_acc(acc);
    gemm_waveB(gate_wb, As, acc, lane, c0w);
    // xg = silu(acc+gb) -> Ss (persists until y-epilogue)
    #pragma unroll
    for(int fc = 0; fc < 4; ++fc){
      const int col = c0w + fc*16 + lr;
      const float gb = gate_bv[col];
      #pragma unroll
      for(int fr = 0; fr < 4; ++fr){
        const int row = fr*16 + rb;
        float v0 = silu_f(acc[fr][fc][0] + gb), v1 = silu_f(acc[fr][fc][1] + gb);
        float v2 = silu_f(acc[fr][fc][2] + gb), v3 = silu_f(acc[fr][fc][3] + gb);
        unsigned p0 = pk_bf16(v0, v1), p1 = pk_bf16(v2, v3);
        *(unsigned short*)(Ss + swzA(row+0, col*2)) = (unsigned short)p0;
        *(unsigned short*)(Ss + swzA(row+1, col*2)) = (unsigned short)(p0 >> 16);
        *(unsigned short*)(Ss + swzA(row+2, col*2)) = (unsigned short)p1;
        *(unsigned short*)(Ss + swzA(row+3, col*2)) = (unsigned short)(p1 >> 16);
      }
    }
    __syncthreads();                                   // S2
    zero_acc(acc);
    gemm_waveB(sp_wb, Ss, acc, lane, c0w);
    // s = acc + sp_b -> As
    #pragma unroll
    for(int fc = 0; fc < 4; ++fc){
      const int col = c0w + fc*16 + lr;
      const float sb = sp_bv[col];
      #pragma unroll
      for(int fr = 0; fr < 4; ++fr){
        const int row = fr*16 + rb;
        unsigned p0 = pk_bf16(acc[fr][fc][0] + sb, acc[fr][fc][1] + sb);
        unsigned p1 = pk_bf16(acc[fr][fc][2] + sb, acc[fr][fc][3] + sb);
        *(unsigned short*)(As + swzA(row+0, col*2)) = (unsigned short)p0;
        *(unsigned short*)(As + swzA(row+1, col*2)) = (unsigned short)(p0 >> 16);
        *(unsigned short*)(As + swzA(row+2, col*2)) = (unsigned short)p1;
        *(unsigned short*)(As + swzA(row+3, col*2)) = (unsigned short)(p1 >> 16);
      }
    }
    __syncthreads();                                   // S3
    // ---- scan (thread = channel), chunked 16 ----
    #pragma unroll
    for(int c4 = 0; c4 < 4; ++c4){
      const int base = c4*16;
      float v[16];
      #pragma unroll
      for(int j = 0; j < 16; ++j)
        v[j] = bf2f(*(const unsigned short*)(As + swzA(base+j, tid*2)));
      #pragma unroll
      for(int j = 0; j < 16; ++j){ st = st*dc + v[j]; v[j] = st; }
      #pragma unroll
      for(int j = 0; j < 8; ++j){
        unsigned p = pk_bf16(v[2*j], v[2*j+1]);
        *(unsigned short*)(As + swzA(base+2*j,   tid*2)) = (unsigned short)p;
        *(unsigned short*)(As + swzA(base+2*j+1, tid*2)) = (unsigned short)(p >> 16);
      }
    }
    __syncthreads();                                   // S4
    zero_acc(acc);
    gemm_waveB(spT_wb, As, acc, lane, c0w);            // y1 = states@sp_w
    __syncthreads();                                   // S5
    // y = acc + D*xg (xg from Ss) -> As
    #pragma unroll
    for(int fc = 0; fc < 4; ++fc){
      const int col = c0w + fc*16 + lr;
      const float Dv = D_v[col];
      #pragma unroll
      for(int fr = 0; fr < 4; ++fr){
        const int row = fr*16 + rb;
        float y0 = acc[fr][fc][0] + Dv*bf2f(*(const unsigned short*)(Ss + swzA(row+0, col*2)));
        float y1 = acc[fr][fc][1] + Dv*bf2f(*(const unsigned short*)(Ss + swzA(row+1, col*2)));
        float y2 = acc[fr][fc][2] + Dv*bf2f(*(const unsigned short*)(Ss + swzA(row+2, col*2)));
        float y3 = acc[fr][fc][3] + Dv*bf2f(*(const unsigned short*)(Ss + swzA(row+3, col*2)));
        unsigned p0 = pk_bf16(y0, y1), p1 = pk_bf16(y2, y3);
        *(unsigned short*)(As + swzA(row+0, col*2)) = (unsigned short)p0;
        *(unsigned short*)(As + swzA(row+1, col*2)) = (unsigned short)(p0 >> 16);
        *(unsigned short*)(As + swzA(row+2, col*2)) = (unsigned short)p1;
        *(unsigned short*)(As + swzA(row+3, col*2)) = (unsigned short)(p1 >> 16);
      }
    }
    __syncthreads();                                   // S6
    zero_acc(acc);
    gemm_waveB(op_wb, As, acc, lane, c0w);             // @op^T
    // acc + op_b -> Ss
    #pragma unroll
    for(int fc = 0; fc < 4; ++fc){
      const int col = c0w + fc*16 + lr;
      const float ob = op_bv[col];
      #pragma unroll
      for(int fr = 0; fr < 4; ++fr){
        const int row = fr*16 + rb;
        unsigned p0 = pk_bf16(acc[fr][fc][0] + ob, acc[fr][fc][1] + ob);
        unsigned p1 = pk_bf16(acc[fr][fc][2] + ob, acc[fr][fc][3] + ob);
        *(unsigned short*)(Ss + swzA(row+0, col*2)) = (unsigned short)p0;
        *(unsigned short*)(Ss + swzA(row+1, col*2)) = (unsigned short)(p0 >> 16);
        *(unsigned short*)(Ss + swzA(row+2, col*2)) = (unsigned short)p1;
        *(unsigned short*)(Ss + swzA(row+3, col*2)) = (unsigned short)(p1 >> 16);
      }
    }
    __syncthreads();                                   // S7
    // ---- Phase G: prefetch next-tile h -> hvn; h(tile) = hv + Ss (LN layout) ----
    short8 hvn[8];
    if(kb < 7){
      const unsigned short* src = h_g + (size_t)(m0 + 64 + rA)*DMODEL + cA;
      #pragma unroll
      for(int i = 0; i < 8; ++i) hvn[i] = __builtin_nontemporal_load((const short8*)(src + i*8));
    }
    {
      unsigned short* dst = h_g + (size_t)(m0 + rA)*DMODEL + cA;
      #pragma unroll
      for(int i = 0; i < 8; ++i){
        short8 a = *(const short8*)(As + 0*As[0], Ss + swzA(rA, cA*2 + i*16)) ; // see below
        // (expression kept simple:)
        a = *(const short8*)(Ss + swzA(rA, cA*2 + i*16));
        u32x4 o;
        #pragma unroll
        for(int j = 0; j < 4; ++j){
          float s0 = bf2f((unsigned short)a[2*j])   + bf2f((unsigned short)hv[i][2*j]);
          float s1 = bf2f((unsigned short)a[2*j+1]) + bf2f((unsigned short)hv[i][2*j+1]);
          o[j] = pk_bf16(s0, s1);
        }
        __builtin_nontemporal_store(o, (u32x4*)(dst + i*8));
      }
    }
    if(kb < 7){
      #pragma unroll
      for(int i = 0; i < 8; ++i) hv[i] = hvn[i];
    }
  }
  state_buf[n*256 + tid] = st;
}

// ---------------- out = gelu(LN(h[:,511,:] @ out_w^T + out_b)) ----------------
__global__ __launch_bounds__(256) void k_out(
    const unsigned short* __restrict__ h_g,
    const unsigned short* __restrict__ out_wb,
    const float* __restrict__ out_bv,
    const float* __restrict__ ln_gv, const float* __restrict__ ln_bv,
    float* __restrict__ out_g)
{
  __shared__ char smem[65536];
  char* As = smem; char* Bs = smem + 32768;
  const int tid = threadIdx.x;
  const int r0 = blockIdx.x * 64;
  const int lane = tid & 63, c0w = (tid>>6)*64, lr = lane & 15, rb = (lane>>4)*4;
  {
    const int r = tid >> 2, c0 = (tid & 3) * 64;
    const unsigned short* src = h_g + ((size_t)(r0 + r)*KSEQ + (KSEQ-1))*DMODEL + c0;
    #pragma unroll
    for(int i = 0; i < 8; ++i){
      short8 v = *(const short8*)(src + i*8);
      *(short8*)(As + swzA(r, c0*2 + i*16)) = v;
    }
  }
  f32x4 acc[4][4]; zero_acc(acc);
  gemm_64x256<4>(out_wb, As, Bs, acc, tid);
  __syncthreads();
  #pragma unroll
  for(int fc = 0; fc < 4; ++fc){
    const int col = c0w + fc*16 + lr;
    const float bb = out_bv[col];
    #pragma unroll
    for(int fr = 0; fr < 4; ++fr)
      #pragma unroll
      for(int rg = 0; rg < 4; ++rg){
        const int row = fr*16 + rb + rg;
        *(float*)(smem + (((unsigned)(row*1024 + col*4)) ^ ((row&7)<<4))) = acc[fr][fc][rg] + bb;
      }
  }
  __syncthreads();
  {
    const int r = tid >> 2, c0 = (tid & 3) * 64;
    float vals[64]; float sm = 0.f, sq = 0.f;
    #pragma unroll
    for(int i = 0; i < 16; ++i){
      float4 v = *(const float4*)(smem + (((unsigned)(r*1024 + (c0 + i*4)*4)) ^ ((r&7)<<4)));
      vals[4*i]=v.x; vals[4*i+1]=v.y; vals[4*i+2]=v.z; vals[4*i+3]=v.w;
    }
    #pragma unroll
    for(int i = 0; i < 64; ++i){ sm += vals[i]; sq += vals[i]*vals[i]; }
    sm += __shfl_xor(sm, 1); sm += __shfl_xor(sm, 2);
    sq += __shfl_xor(sq, 1); sq += __shfl_xor(sq, 2);
    const float mu = sm * (1.f/256.f);
    const float rstd = rsqrtf(sq * (1.f/256.f) - mu*mu + 1e-5f);
    float* dst = out_g + (size_t)(r0 + r)*DMODEL + c0;
    #pragma unroll
    for(int i = 0; i < 16; ++i){
      float4 o;
      o.x = gelu_f((vals[4*i+0]-mu)*rstd*ln_gv[c0+i*4+0] + ln_bv[c0+i*4+0]);
      o.y = gelu_f((vals[4*i+1]-mu)*rstd*ln_gv[c0+i*4+1] + ln_bv[c0+i*4+1]);
      o.z = gelu_f((vals[4*i+2]-mu)*rstd*ln_gv[c0+i*4+2] + ln_bv[c0+i*4+2]);
      o.w = gelu_f((vals[4*i+3]-mu)*rstd*ln_gv[c0+i*4+3] + ln_bv[c0+i*4+3]);
      *(float4*)(dst + i*4) = o;
    }
  }
}

extern "C" void kernel_launch(void* const* d_in, const int* in_sizes, int n_in,
                              void* d_out, int out_size, void* d_ws, size_t ws_size,
                              hipStream_t stream) {
  (void)in_sizes; (void)n_in; (void)out_size; (void)ws_size;
  const float* x        = (const float*)d_in[0];
  const float* in_w     = (const float*)d_in[1];
  const float* in_b     = (const float*)d_in[2];
  const float* in_ln_g  = (const float*)d_in[3];
  const float* in_ln_b  = (const float*)d_in[4];
  const float* ln_g     = (const float*)d_in[5];
  const float* ln_b     = (const float*)d_in[6];
  const float* gate_w   = (const float*)d_in[7];
  const float* gate_b   = (const float*)d_in[8];
  const float* sp_w     = (const float*)d_in[9];
  const float* sp_b     = (const float*)d_in[10];
  const float* op_w     = (const float*)d_in[11];
  const float* op_b     = (const float*)d_in[12];
  const float* A_log    = (const float*)d_in[13];
  const float* Dp       = (const float*)d_in[14];
  const float* out_w    = (const float*)d_in[15];
  const float* out_b    = (const float*)d_in[16];
  const float* out_ln_g = (const float*)d_in[17];
  const float* out_ln_b = (const float*)d_in[18];

  char* ws = (char*)d_ws;
  // ~133.7 MiB workspace (proven budget)
  unsigned short* h_g       = (unsigned short*)(ws + 0);           // 128 MiB
  float*          state_buf = (float*)(ws + 134217728);            // 512 KiB
  float*          decay     = (float*)(ws + 134742016);            // 2 KiB
  unsigned short* wbase     = (unsigned short*)(ws + 134744064);   // ~1.2 MiB
  unsigned short* in_wb  = wbase;               // 32768
  unsigned short* gate_wb= in_wb  + 32768;      // 2*65536
  unsigned short* sp_wb  = gate_wb+ 131072;
  unsigned short* sp_wTb = sp_wb  + 131072;
  unsigned short* op_wb  = sp_wTb + 131072;
  unsigned short* out_wb = op_wb  + 131072;     // 65536

  // prep
  k_cvt_inw<<<128, 256, 0, stream>>>(in_w, in_wb);
  k_cvt<<<512, 256, 0, stream>>>(gate_w, gate_wb, 131072);
  k_cvt<<<512, 256, 0, stream>>>(sp_w,   sp_wb,   131072);
  k_cvt<<<512, 256, 0, stream>>>(op_w,   op_wb,   131072);
  k_cvt<<<256, 256, 0, stream>>>(out_w,  out_wb,  65536);
  k_spT<<<dim3(256,2), 256, 0, stream>>>(sp_w, sp_wTb);
  k_decay<<<512, 256, 0, stream>>>(A_log, decay);

  // pipeline
  k_in_proj<<<MTOT/64, 256, 0, stream>>>(x, in_wb, in_b, in_ln_g, in_ln_b, h_g);
  for(int l = 0; l < 2; ++l){
    k_layer<<<NSEQ, 256, 0, stream>>>(h_g,
        gate_wb + l*65536, sp_wb + l*65536, sp_wTb + l*65536, op_wb + l*65536,
        ln_g + l*256, ln_b + l*256, gate_b + l*256, sp_b + l*256,
        decay + l*256, Dp + l*256, op_b + l*256, state_buf, l);
  }
  k_out<<<NSEQ/64, 256, 0, stream>>>(h_g, out_wb, out_b, out_ln_g, out_ln_b, (float*)d_out);
}

// Round 8
// 2342.710 us; speedup vs baseline: 1.1423x; 1.1423x over previous
//
#include <hip/hip_runtime.h>
#include <hip/hip_bf16.h>

// MambaEncoder on MI355X — v8: v5 structure (best: 581us/layer) +
//  (1) cross-phase register pipeline for weight panels: each wave holds its
//      32KB panel-quarter in Bp[32] VGPRs; during GEMM p each consumed chunk
//      is reloaded with GEMM p+1's panel -> loads get a full phase to land.
//  (2) raw s_barrier + explicit lgkmcnt(0) (no vmcnt drain) so those loads
//      stay in flight across barriers (T3/T4 pattern).
// No nontemporal anywhere (v7 lesson: nt + non-wave-contiguous 16B = 4x
// sector amplification). v5-verbatim epilogues/scan/RMW.

typedef __attribute__((ext_vector_type(8))) __bf16 bf16x8;
typedef __attribute__((ext_vector_type(8))) short short8;
typedef __attribute__((ext_vector_type(4))) float f32x4;
typedef __attribute__((ext_vector_type(4))) unsigned u32x4;

#define NSEQ 512
#define KSEQ 512
#define FIN 96
#define DMODEL 256
#define MTOT (NSEQ*KSEQ)

__device__ __forceinline__ unsigned short f2bf(float f){
  union { float f; unsigned u; } v; v.f = f;
  unsigned r = (v.u + 0x7FFFu + ((v.u >> 16) & 1u)) >> 16;
  return (unsigned short)r;
}
__device__ __forceinline__ float bf2f(unsigned short b){
  union { unsigned u; float f; } v; v.u = ((unsigned)b) << 16; return v.f;
}
__device__ __forceinline__ unsigned pk_bf16(float lo, float hi){
  unsigned r;
  asm("v_cvt_pk_bf16_f32 %0, %1, %2" : "=v"(r) : "v"(lo), "v"(hi));
  return r;
}
__device__ __forceinline__ float gelu_f(float x){
  return 0.5f * x * (1.0f + erff(x * 0.70710678118654752440f));
}
__device__ __forceinline__ float silu_f(float x){
  return x / (1.0f + __expf(-x));
}
// LDS barrier WITHOUT vmcnt drain: waits LDS ops only, then raw barrier.
__device__ __forceinline__ void barx(){
  asm volatile("s_waitcnt lgkmcnt(0)" ::: "memory");
  __builtin_amdgcn_s_barrier();
}
__device__ __forceinline__ unsigned swzA(int row, int kbyte){   // [64][256] bf16, 512B stride
  return ((unsigned)(row*512 + kbyte)) ^ (unsigned)((row & 7) << 4);
}
__device__ __forceinline__ unsigned swzB(int n, int kbyte){     // [256][64] bf16
  return ((unsigned)(n*128 + kbyte)) ^ (unsigned)((n & 7) << 4);
}

__device__ __forceinline__ void zero_acc(f32x4 (&acc)[4][4]){
  #pragma unroll
  for(int a=0;a<4;++a)
    #pragma unroll
    for(int b=0;b<4;++b)
      acc[a][b] = (f32x4){0.f,0.f,0.f,0.f};
}

// load this wave's quarter (64 cols x 256 k = 32KB) of panel wb into Bp
__device__ __forceinline__ void load_panel(bf16x8 (&Bp)[32],
    const unsigned short* __restrict__ wb, int lane, int c0)
{
  const int lr = lane & 15, lk8 = (lane >> 4) * 8;
  const unsigned short* p = wb + (size_t)(c0 + lr)*256 + lk8;
  #pragma unroll
  for(int kc = 0; kc < 8; ++kc)
    #pragma unroll
    for(int fc = 0; fc < 4; ++fc)
      Bp[kc*4+fc] = *(const bf16x8*)(p + fc*4096 + kc*32);
}

// pipelined per-wave GEMM: acc += A(64x256 LDS, swzA) @ panel-in-Bp^T.
// As each chunk is consumed, its registers are refilled with panel `nxt`
// (for the NEXT GEMM phase) -> a full phase of latency cover.
__device__ __forceinline__ void gemm_pipe(const char* Asrc, f32x4 (&acc)[4][4],
    bf16x8 (&Bp)[32], const unsigned short* __restrict__ nxt, int lane, int c0)
{
  const int lr  = lane & 15;
  const int lk8 = (lane >> 4) * 8;
  const unsigned short* np = nxt + (size_t)(c0 + lr)*256 + lk8;
  #pragma unroll
  for(int kc = 0; kc < 8; ++kc){
    bf16x8 af[4];
    #pragma unroll
    for(int fr = 0; fr < 4; ++fr)
      af[fr] = *(const bf16x8*)(Asrc + swzA(fr*16 + lr, kc*64 + lk8*2));
    #pragma unroll
    for(int fr = 0; fr < 4; ++fr)
      #pragma unroll
      for(int fc = 0; fc < 4; ++fc)
        acc[fr][fc] = __builtin_amdgcn_mfma_f32_16x16x32_bf16(af[fr], Bp[kc*4+fc], acc[fr][fc], 0, 0, 0);
    #pragma unroll
    for(int fc = 0; fc < 4; ++fc)
      Bp[kc*4+fc] = *(const bf16x8*)(np + fc*4096 + kc*32);
  }
}

// LDS-staged GEMM (k_in_proj / k_out only, proven)
template<int KCH>
__device__ __forceinline__ void gemm_64x256(const unsigned short* __restrict__ wb,
                                            char* As, char* Bs,
                                            f32x4 (&acc)[4][4], int tid)
{
  const int lane = tid & 63;
  const int c0   = (tid >> 6) * 64;
  const int lr   = lane & 15;
  const int lk16 = (lane >> 4) * 16;
  #pragma unroll
  for(int kc = 0; kc < KCH; ++kc){
    __syncthreads();
    {
      const unsigned short* src = wb + (size_t)tid * (KCH*64) + kc*64;
      #pragma unroll
      for(int i = 0; i < 8; ++i){
        short8 v = *(const short8*)(src + i*8);
        *(short8*)(Bs + swzB(tid, i*16)) = v;
      }
    }
    __syncthreads();
    #pragma unroll
    for(int t2 = 0; t2 < 2; ++t2){
      bf16x8 af[4], bfr[4];
      #pragma unroll
      for(int fr = 0; fr < 4; ++fr)
        af[fr] = *(const bf16x8*)(As + swzA(fr*16 + lr, kc*128 + t2*64 + lk16));
      #pragma unroll
      for(int fc = 0; fc < 4; ++fc)
        bfr[fc] = *(const bf16x8*)(Bs + swzB(c0 + fc*16 + lr, t2*64 + lk16));
      #pragma unroll
      for(int fr = 0; fr < 4; ++fr)
        #pragma unroll
        for(int fc = 0; fc < 4; ++fc)
          acc[fr][fc] = __builtin_amdgcn_mfma_f32_16x16x32_bf16(af[fr], bfr[fc], acc[fr][fc], 0, 0, 0);
    }
  }
}

// ---------------- prep kernels ----------------
__global__ void k_cvt(const float* __restrict__ s, unsigned short* __restrict__ d, int n){
  int i = blockIdx.x*256 + threadIdx.x;
  if(i < n) d[i] = f2bf(s[i]);
}
__global__ void k_cvt_inw(const float* __restrict__ w, unsigned short* __restrict__ d){
  int i = blockIdx.x*256 + threadIdx.x;
  int n = i >> 7, f = i & 127;
  d[i] = (f < 96) ? f2bf(w[n*96 + f]) : (unsigned short)0;
}
__global__ void k_spT(const float* __restrict__ spw, unsigned short* __restrict__ d){
  int l = blockIdx.y;
  int i = blockIdx.x*256 + threadIdx.x;
  int dd = i >> 8, ss = i & 255;
  d[l*65536 + i] = f2bf(spw[l*65536 + ss*256 + dd]);
}
__global__ void k_decay(const float* __restrict__ A_log, float* __restrict__ decay){
  __shared__ float red[4];
  const int b = blockIdx.x;            // l*256 + d
  const int tid = threadIdx.x;
  float v = expf(A_log[(size_t)b*256 + tid]);
  #pragma unroll
  for(int o = 32; o >= 1; o >>= 1) v += __shfl_xor(v, o);
  if((tid & 63) == 0) red[tid >> 6] = v;
  __syncthreads();
  if(tid == 0){
    float s = red[0] + red[1] + red[2] + red[3];
    decay[b] = expf(-s * (1.f/256.f));
  }
}

// ---------------- h = gelu(LN(x @ in_w^T + in_b)) -> bf16 (v5 verbatim) ----------------
__global__ __launch_bounds__(256) void k_in_proj(
    const float* __restrict__ x_g,
    const unsigned short* __restrict__ in_wb,
    const float* __restrict__ in_b,
    const float* __restrict__ ln_gv, const float* __restrict__ ln_bv,
    unsigned short* __restrict__ h_g)
{
  __shared__ char smem[65536];
  char* As = smem; char* Bs = smem + 32768;
  const int tid = threadIdx.x;
  const int m0 = blockIdx.x * 64;
  const int lane = tid & 63, c0w = (tid>>6)*64, lr = lane & 15, rb = (lane>>4)*4;
  {
    const int r = tid >> 2, cq = tid & 3;
    const float* src = x_g + (size_t)(m0 + r)*FIN + cq*24;
    unsigned short tmp[24] __attribute__((aligned(16)));
    #pragma unroll
    for(int i = 0; i < 6; ++i){
      float4 v = *(const float4*)(src + i*4);
      tmp[4*i]=f2bf(v.x); tmp[4*i+1]=f2bf(v.y); tmp[4*i+2]=f2bf(v.z); tmp[4*i+3]=f2bf(v.w);
    }
    #pragma unroll
    for(int i = 0; i < 3; ++i)
      *(short8*)(As + swzA(r, cq*48 + i*16)) = *(const short8*)(tmp + i*8);
    if(cq == 3){
      short8 z8 = {0,0,0,0,0,0,0,0};
      #pragma unroll
      for(int i = 0; i < 4; ++i)
        *(short8*)(As + swzA(r, 192 + i*16)) = z8;
    }
  }
  f32x4 acc[4][4]; zero_acc(acc);
  gemm_64x256<2>(in_wb, As, Bs, acc, tid);
  __syncthreads();
  #pragma unroll
  for(int fc = 0; fc < 4; ++fc){
    const int col = c0w + fc*16 + lr;
    const float bb = in_b[col];
    #pragma unroll
    for(int fr = 0; fr < 4; ++fr)
      #pragma unroll
      for(int rg = 0; rg < 4; ++rg){
        const int row = fr*16 + rb + rg;
        *(float*)(smem + (((unsigned)(row*1024 + col*4)) ^ ((row&7)<<4))) = acc[fr][fc][rg] + bb;
      }
  }
  __syncthreads();
  {
    const int r = tid >> 2, c0 = (tid & 3) * 64;
    float vals[64]; float sm = 0.f, sq = 0.f;
    #pragma unroll
    for(int i = 0; i < 16; ++i){
      float4 v = *(const float4*)(smem + (((unsigned)(r*1024 + (c0 + i*4)*4)) ^ ((r&7)<<4)));
      vals[4*i]=v.x; vals[4*i+1]=v.y; vals[4*i+2]=v.z; vals[4*i+3]=v.w;
    }
    #pragma unroll
    for(int i = 0; i < 64; ++i){ sm += vals[i]; sq += vals[i]*vals[i]; }
    sm += __shfl_xor(sm, 1); sm += __shfl_xor(sm, 2);
    sq += __shfl_xor(sq, 1); sq += __shfl_xor(sq, 2);
    const float mu = sm * (1.f/256.f);
    const float rstd = rsqrtf(sq * (1.f/256.f) - mu*mu + 1e-5f);
    unsigned short* dst = h_g + (size_t)(m0 + r)*DMODEL + c0;
    #pragma unroll
    for(int i = 0; i < 8; ++i){
      float g[8];
      #pragma unroll
      for(int j = 0; j < 8; ++j){
        const int c = c0 + i*8 + j;
        g[j] = gelu_f((vals[i*8+j]-mu)*rstd*ln_gv[c] + ln_bv[c]);
      }
      u32x4 o;
      o[0] = pk_bf16(g[0],g[1]); o[1] = pk_bf16(g[2],g[3]);
      o[2] = pk_bf16(g[4],g[5]); o[3] = pk_bf16(g[6],g[7]);
      *(u32x4*)(dst + i*8) = o;
    }
  }
}

// ---------------- full layer: block = sequence, 8 serial tiles, exact scan ----------------
__global__ __launch_bounds__(256,2) void k_layer(
    unsigned short* __restrict__ h_g,
    const unsigned short* __restrict__ gate_wb,
    const unsigned short* __restrict__ sp_wb,
    const unsigned short* __restrict__ spT_wb,
    const unsigned short* __restrict__ op_wb,
    const float* __restrict__ ln_gv, const float* __restrict__ ln_bv,
    const float* __restrict__ gate_bv, const float* __restrict__ sp_bv,
    const float* __restrict__ decay_v, const float* __restrict__ D_v,
    const float* __restrict__ op_bv,
    float* __restrict__ state_buf, const int layer)
{
  __shared__ char As[32768];
  __shared__ char Ss[32768];
  const int tid = threadIdx.x;
  const int n = blockIdx.x;
  const int lane = tid & 63, c0w = (tid>>6)*64, lr = lane & 15, rb = (lane>>4)*4;
  const float dc = decay_v[tid];
  float st = (layer > 0) ? state_buf[n*256 + tid] : 0.f;

  // panel pipeline register file: this wave's 32KB quarter of one weight panel
  bf16x8 Bp[32];
  load_panel(Bp, gate_wb, lane, c0w);

  #pragma unroll 1
  for(int kb = 0; kb < 8; ++kb){
    const int m0 = n*KSEQ + kb*64;
    // ---- Phase A: LN(h) -> z bf16 in As ----
    {
      const int r = tid >> 2, c0 = (tid & 3) * 64;
      const unsigned short* src = h_g + (size_t)(m0 + r)*DMODEL + c0;
      short8 hv[8];
      #pragma unroll
      for(int i = 0; i < 8; ++i) hv[i] = *(const short8*)(src + i*8);
      float sm = 0.f, sq = 0.f;
      #pragma unroll
      for(int i = 0; i < 8; ++i)
        #pragma unroll
        for(int j = 0; j < 8; ++j){
          float v = bf2f((unsigned short)hv[i][j]); sm += v; sq += v*v;
        }
      sm += __shfl_xor(sm, 1); sm += __shfl_xor(sm, 2);
      sq += __shfl_xor(sq, 1); sq += __shfl_xor(sq, 2);
      const float mu = sm * (1.f/256.f);
      const float rstd = rsqrtf(sq * (1.f/256.f) - mu*mu + 1e-5f);
      #pragma unroll
      for(int i = 0; i < 8; ++i){
        float z[8];
        #pragma unroll
        for(int j = 0; j < 8; ++j){
          const int c = c0 + i*8 + j;
          z[j] = (bf2f((unsigned short)hv[i][j])-mu)*rstd*ln_gv[c] + ln_bv[c];
        }
        u32x4 zz;
        zz[0] = pk_bf16(z[0],z[1]); zz[1] = pk_bf16(z[2],z[3]);
        zz[2] = pk_bf16(z[4],z[5]); zz[3] = pk_bf16(z[6],z[7]);
        *(u32x4*)(As + swzA(r, c0*2 + i*16)) = zz;
      }
    }
    barx();                                            // S1
    f32x4 acc[4][4]; zero_acc(acc);
    gemm_pipe(As, acc, Bp, sp_wb, lane, c0w);          // gate GEMM; prefetch sp
    // xg = silu(acc+gb) -> Ss (persists until y-epilogue)
    #pragma unroll
    for(int fc = 0; fc < 4; ++fc){
      const int col = c0w + fc*16 + lr;
      const float gb = gate_bv[col];
      #pragma unroll
      for(int fr = 0; fr < 4; ++fr){
        const int row = fr*16 + rb;
        float v0 = silu_f(acc[fr][fc][0] + gb), v1 = silu_f(acc[fr][fc][1] + gb);
        float v2 = silu_f(acc[fr][fc][2] + gb), v3 = silu_f(acc[fr][fc][3] + gb);
        unsigned p0 = pk_bf16(v0, v1), p1 = pk_bf16(v2, v3);
        *(unsigned short*)(Ss + swzA(row+0, col*2)) = (unsigned short)p0;
        *(unsigned short*)(Ss + swzA(row+1, col*2)) = (unsigned short)(p0 >> 16);
        *(unsigned short*)(Ss + swzA(row+2, col*2)) = (unsigned short)p1;
        *(unsigned short*)(Ss + swzA(row+3, col*2)) = (unsigned short)(p1 >> 16);
      }
    }
    barx();                                            // S2
    zero_acc(acc);
    gemm_pipe(Ss, acc, Bp, spT_wb, lane, c0w);         // sp GEMM; prefetch spT
    // s = acc + sp_b -> As
    #pragma unroll
    for(int fc = 0; fc < 4; ++fc){
      const int col = c0w + fc*16 + lr;
      const float sb = sp_bv[col];
      #pragma unroll
      for(int fr = 0; fr < 4; ++fr){
        const int row = fr*16 + rb;
        unsigned p0 = pk_bf16(acc[fr][fc][0] + sb, acc[fr][fc][1] + sb);
        unsigned p1 = pk_bf16(acc[fr][fc][2] + sb, acc[fr][fc][3] + sb);
        *(unsigned short*)(As + swzA(row+0, col*2)) = (unsigned short)p0;
        *(unsigned short*)(As + swzA(row+1, col*2)) = (unsigned short)(p0 >> 16);
        *(unsigned short*)(As + swzA(row+2, col*2)) = (unsigned short)p1;
        *(unsigned short*)(As + swzA(row+3, col*2)) = (unsigned short)(p1 >> 16);
      }
    }
    barx();                                            // S3
    // ---- scan (thread = channel), chunked 16 ----
    #pragma unroll
    for(int c4 = 0; c4 < 4; ++c4){
      const int base = c4*16;
      float v[16];
      #pragma unroll
      for(int j = 0; j < 16; ++j)
        v[j] = bf2f(*(const unsigned short*)(As + swzA(base+j, tid*2)));
      #pragma unroll
      for(int j = 0; j < 16; ++j){ st = st*dc + v[j]; v[j] = st; }
      #pragma unroll
      for(int j = 0; j < 8; ++j){
        unsigned p = pk_bf16(v[2*j], v[2*j+1]);
        *(unsigned short*)(As + swzA(base+2*j,   tid*2)) = (unsigned short)p;
        *(unsigned short*)(As + swzA(base+2*j+1, tid*2)) = (unsigned short)(p >> 16);
      }
    }
    barx();                                            // S4
    zero_acc(acc);
    gemm_pipe(As, acc, Bp, op_wb, lane, c0w);          // spT GEMM; prefetch op
    barx();                                            // S5
    // y = acc + D*xg (xg from Ss) -> As
    #pragma unroll
    for(int fc = 0; fc < 4; ++fc){
      const int col = c0w + fc*16 + lr;
      const float Dv = D_v[col];
      #pragma unroll
      for(int fr = 0; fr < 4; ++fr){
        const int row = fr*16 + rb;
        float y0 = acc[fr][fc][0] + Dv*bf2f(*(const unsigned short*)(Ss + swzA(row+0, col*2)));
        float y1 = acc[fr][fc][1] + Dv*bf2f(*(const unsigned short*)(Ss + swzA(row+1, col*2)));
        float y2 = acc[fr][fc][2] + Dv*bf2f(*(const unsigned short*)(Ss + swzA(row+2, col*2)));
        float y3 = acc[fr][fc][3] + Dv*bf2f(*(const unsigned short*)(Ss + swzA(row+3, col*2)));
        unsigned p0 = pk_bf16(y0, y1), p1 = pk_bf16(y2, y3);
        *(unsigned short*)(As + swzA(row+0, col*2)) = (unsigned short)p0;
        *(unsigned short*)(As + swzA(row+1, col*2)) = (unsigned short)(p0 >> 16);
        *(unsigned short*)(As + swzA(row+2, col*2)) = (unsigned short)p1;
        *(unsigned short*)(As + swzA(row+3, col*2)) = (unsigned short)(p1 >> 16);
      }
    }
    barx();                                            // S6
    zero_acc(acc);
    gemm_pipe(As, acc, Bp, gate_wb, lane, c0w);        // op GEMM; prefetch next gate
    // acc + op_b -> Ss
    #pragma unroll
    for(int fc = 0; fc < 4; ++fc){
      const int col = c0w + fc*16 + lr;
      const float ob = op_bv[col];
      #pragma unroll
      for(int fr = 0; fr < 4; ++fr){
        const int row = fr*16 + rb;
        unsigned p0 = pk_bf16(acc[fr][fc][0] + ob, acc[fr][fc][1] + ob);
        unsigned p1 = pk_bf16(acc[fr][fc][2] + ob, acc[fr][fc][3] + ob);
        *(unsigned short*)(Ss + swzA(row+0, col*2)) = (unsigned short)p0;
        *(unsigned short*)(Ss + swzA(row+1, col*2)) = (unsigned short)(p0 >> 16);
        *(unsigned short*)(Ss + swzA(row+2, col*2)) = (unsigned short)p1;
        *(unsigned short*)(Ss + swzA(row+3, col*2)) = (unsigned short)(p1 >> 16);
      }
    }
    barx();                                            // S7
    // h += (y@op^T + op_b), coalesced RMW from Ss (v5 verbatim)
    {
      char* dst = (char*)(h_g + (size_t)m0*DMODEL);
      #pragma unroll
      for(int i = 0; i < 8; ++i){
        const unsigned flat = (unsigned)(i*4096 + tid*16);
        const unsigned row = flat >> 9;
        short8 a = *(const short8*)(Ss + (flat ^ ((row & 7u) << 4)));
        short8 hv = *(const short8*)(dst + flat);
        u32x4 o;
        #pragma unroll
        for(int j = 0; j < 4; ++j){
          float s0 = bf2f((unsigned short)a[2*j])   + bf2f((unsigned short)hv[2*j]);
          float s1 = bf2f((unsigned short)a[2*j+1]) + bf2f((unsigned short)hv[2*j+1]);
          o[j] = pk_bf16(s0, s1);
        }
        *(u32x4*)(dst + flat) = o;
      }
    }
    // next tile's Phase A writes As (all As reads drained at S7)
  }
  state_buf[n*256 + tid] = st;
}

// ---------------- out = gelu(LN(h[:,511,:] @ out_w^T + out_b)) (v5 verbatim) ----------------
__global__ __launch_bounds__(256) void k_out(
    const unsigned short* __restrict__ h_g,
    const unsigned short* __restrict__ out_wb,
    const float* __restrict__ out_bv,
    const float* __restrict__ ln_gv, const float* __restrict__ ln_bv,
    float* __restrict__ out_g)
{
  __shared__ char smem[65536];
  char* As = smem; char* Bs = smem + 32768;
  const int tid = threadIdx.x;
  const int r0 = blockIdx.x * 64;
  const int lane = tid & 63, c0w = (tid>>6)*64, lr = lane & 15, rb = (lane>>4)*4;
  {
    const int r = tid >> 2, c0 = (tid & 3) * 64;
    const unsigned short* src = h_g + ((size_t)(r0 + r)*KSEQ + (KSEQ-1))*DMODEL + c0;
    #pragma unroll
    for(int i = 0; i < 8; ++i){
      short8 v = *(const short8*)(src + i*8);
      *(short8*)(As + swzA(r, c0*2 + i*16)) = v;
    }
  }
  f32x4 acc[4][4]; zero_acc(acc);
  gemm_64x256<4>(out_wb, As, Bs, acc, tid);
  __syncthreads();
  #pragma unroll
  for(int fc = 0; fc < 4; ++fc){
    const int col = c0w + fc*16 + lr;
    const float bb = out_bv[col];
    #pragma unroll
    for(int fr = 0; fr < 4; ++fr)
      #pragma unroll
      for(int rg = 0; rg < 4; ++rg){
        const int row = fr*16 + rb + rg;
        *(float*)(smem + (((unsigned)(row*1024 + col*4)) ^ ((row&7)<<4))) = acc[fr][fc][rg] + bb;
      }
  }
  __syncthreads();
  {
    const int r = tid >> 2, c0 = (tid & 3) * 64;
    float vals[64]; float sm = 0.f, sq = 0.f;
    #pragma unroll
    for(int i = 0; i < 16; ++i){
      float4 v = *(const float4*)(smem + (((unsigned)(r*1024 + (c0 + i*4)*4)) ^ ((r&7)<<4)));
      vals[4*i]=v.x; vals[4*i+1]=v.y; vals[4*i+2]=v.z; vals[4*i+3]=v.w;
    }
    #pragma unroll
    for(int i = 0; i < 64; ++i){ sm += vals[i]; sq += vals[i]*vals[i]; }
    sm += __shfl_xor(sm, 1); sm += __shfl_xor(sm, 2);
    sq += __shfl_xor(sq, 1); sq += __shfl_xor(sq, 2);
    const float mu = sm * (1.f/256.f);
    const float rstd = rsqrtf(sq * (1.f/256.f) - mu*mu + 1e-5f);
    float* dst = out_g + (size_t)(r0 + r)*DMODEL + c0;
    #pragma unroll
    for(int i = 0; i < 16; ++i){
      float4 o;
      o.x = gelu_f((vals[4*i+0]-mu)*rstd*ln_gv[c0+i*4+0] + ln_bv[c0+i*4+0]);
      o.y = gelu_f((vals[4*i+1]-mu)*rstd*ln_gv[c0+i*4+1] + ln_bv[c0+i*4+1]);
      o.z = gelu_f((vals[4*i+2]-mu)*rstd*ln_gv[c0+i*4+2] + ln_bv[c0+i*4+2]);
      o.w = gelu_f((vals[4*i+3]-mu)*rstd*ln_gv[c0+i*4+3] + ln_bv[c0+i*4+3]);
      *(float4*)(dst + i*4) = o;
    }
  }
}

extern "C" void kernel_launch(void* const* d_in, const int* in_sizes, int n_in,
                              void* d_out, int out_size, void* d_ws, size_t ws_size,
                              hipStream_t stream) {
  (void)in_sizes; (void)n_in; (void)out_size; (void)ws_size;
  const float* x        = (const float*)d_in[0];
  const float* in_w     = (const float*)d_in[1];
  const float* in_b     = (const float*)d_in[2];
  const float* in_ln_g  = (const float*)d_in[3];
  const float* in_ln_b  = (const float*)d_in[4];
  const float* ln_g     = (const float*)d_in[5];
  const float* ln_b     = (const float*)d_in[6];
  const float* gate_w   = (const float*)d_in[7];
  const float* gate_b   = (const float*)d_in[8];
  const float* sp_w     = (const float*)d_in[9];
  const float* sp_b     = (const float*)d_in[10];
  const float* op_w     = (const float*)d_in[11];
  const float* op_b     = (const float*)d_in[12];
  const float* A_log    = (const float*)d_in[13];
  const float* Dp       = (const float*)d_in[14];
  const float* out_w    = (const float*)d_in[15];
  const float* out_b    = (const float*)d_in[16];
  const float* out_ln_g = (const float*)d_in[17];
  const float* out_ln_b = (const float*)d_in[18];

  char* ws = (char*)d_ws;
  // ~133.7 MiB workspace (proven budget)
  unsigned short* h_g       = (unsigned short*)(ws + 0);           // 128 MiB
  float*          state_buf = (float*)(ws + 134217728);            // 512 KiB
  float*          decay     = (float*)(ws + 134742016);            // 2 KiB
  unsigned short* wbase     = (unsigned short*)(ws + 134744064);   // ~1.2 MiB
  unsigned short* in_wb  = wbase;               // 32768
  unsigned short* gate_wb= in_wb  + 32768;      // 2*65536
  unsigned short* sp_wb  = gate_wb+ 131072;
  unsigned short* sp_wTb = sp_wb  + 131072;
  unsigned short* op_wb  = sp_wTb + 131072;
  unsigned short* out_wb = op_wb  + 131072;     // 65536

  // prep
  k_cvt_inw<<<128, 256, 0, stream>>>(in_w, in_wb);
  k_cvt<<<512, 256, 0, stream>>>(gate_w, gate_wb, 131072);
  k_cvt<<<512, 256, 0, stream>>>(sp_w,   sp_wb,   131072);
  k_cvt<<<512, 256, 0, stream>>>(op_w,   op_wb,   131072);
  k_cvt<<<256, 256, 0, stream>>>(out_w,  out_wb,  65536);
  k_spT<<<dim3(256,2), 256, 0, stream>>>(sp_w, sp_wTb);
  k_decay<<<512, 256, 0, stream>>>(A_log, decay);

  // pipeline
  k_in_proj<<<MTOT/64, 256, 0, stream>>>(x, in_wb, in_b, in_ln_g, in_ln_b, h_g);
  for(int l = 0; l < 2; ++l){
    k_layer<<<NSEQ, 256, 0, stream>>>(h_g,
        gate_wb + l*65536, sp_wb + l*65536, sp_wTb + l*65536, op_wb + l*65536,
        ln_g + l*256, ln_b + l*256, gate_b + l*256, sp_b + l*256,
        decay + l*256, Dp + l*256, op_b + l*256, state_buf, l);
  }
  k_out<<<NSEQ/64, 256, 0, stream>>>(h_g, out_wb, out_b, out_ln_g, out_ln_b, (float*)d_out);
}

// Round 9
// 1350.849 us; speedup vs baseline: 1.9810x; 1.7343x over previous
//
#include <hip/hip_runtime.h>
#include <hip/hip_bf16.h>

// MambaEncoder on MI355X — v9: v5 (best, 581us/layer) + two targeted fixes:
//  (1) nontemporal STORE only on the final coalesced h-RMW write -> h write-
//      allocate no longer evicts the 512KB weight panels from each XCD L2
//      (v7 lesson: nt is safe ONLY on wave-contiguous full-sector accesses).
//  (2) 4-deep B-chunk prefetch ring in gemm_waveB (v5 was 1-deep); extra
//      64 VGPR free since LDS caps occupancy at 2 blocks/CU.
// Structure: k_in_proj | k_layer x2 (block=sequence, 8 serial tiles, exact
// reg-carried scan, 7 barriers/tile, As/Ss 32KB) | k_out. ws ~133.7MiB.

typedef __attribute__((ext_vector_type(8))) __bf16 bf16x8;
typedef __attribute__((ext_vector_type(8))) short short8;
typedef __attribute__((ext_vector_type(4))) float f32x4;
typedef __attribute__((ext_vector_type(4))) unsigned u32x4;

#define NSEQ 512
#define KSEQ 512
#define FIN 96
#define DMODEL 256
#define MTOT (NSEQ*KSEQ)

__device__ __forceinline__ unsigned short f2bf(float f){
  union { float f; unsigned u; } v; v.f = f;
  unsigned r = (v.u + 0x7FFFu + ((v.u >> 16) & 1u)) >> 16;
  return (unsigned short)r;
}
__device__ __forceinline__ float bf2f(unsigned short b){
  union { unsigned u; float f; } v; v.u = ((unsigned)b) << 16; return v.f;
}
__device__ __forceinline__ unsigned pk_bf16(float lo, float hi){
  unsigned r;
  asm("v_cvt_pk_bf16_f32 %0, %1, %2" : "=v"(r) : "v"(lo), "v"(hi));
  return r;
}
__device__ __forceinline__ float gelu_f(float x){
  return 0.5f * x * (1.0f + erff(x * 0.70710678118654752440f));
}
__device__ __forceinline__ float silu_f(float x){
  return x / (1.0f + __expf(-x));
}
__device__ __forceinline__ unsigned swzA(int row, int kbyte){   // [64][256] bf16, 512B stride
  return ((unsigned)(row*512 + kbyte)) ^ (unsigned)((row & 7) << 4);
}
__device__ __forceinline__ unsigned swzB(int n, int kbyte){     // [256][64] bf16
  return ((unsigned)(n*128 + kbyte)) ^ (unsigned)((n & 7) << 4);
}

__device__ __forceinline__ void zero_acc(f32x4 (&acc)[4][4]){
  #pragma unroll
  for(int a=0;a<4;++a)
    #pragma unroll
    for(int b=0;b<4;++b)
      acc[a][b] = (f32x4){0.f,0.f,0.f,0.f};
}

// per-wave GEMM K=256: acc += A(64x256 bf16 LDS, swzA) @ W[256][256]^T.
// B direct from global with 4-deep chunk prefetch ring (chunk kc+4 issued
// right after chunk kc is consumed -> ~320cy cover, enough for L2 hits).
__device__ __forceinline__ void gemm_waveB(const unsigned short* __restrict__ wb,
                                           const char* As, f32x4 (&acc)[4][4],
                                           int lane, int c0)
{
  const int lr  = lane & 15;
  const int lk8 = (lane >> 4) * 8;
  const unsigned short* bp = wb + (size_t)(c0 + lr)*256 + lk8;   // + fc*4096 + kc*32
  bf16x8 bb[4][4];
  #pragma unroll
  for(int p = 0; p < 4; ++p)
    #pragma unroll
    for(int fc = 0; fc < 4; ++fc)
      bb[p][fc] = *(const bf16x8*)(bp + fc*4096 + p*32);
  #pragma unroll
  for(int kc = 0; kc < 8; ++kc){
    bf16x8 af[4];
    #pragma unroll
    for(int fr = 0; fr < 4; ++fr)
      af[fr] = *(const bf16x8*)(As + swzA(fr*16 + lr, kc*64 + lk8*2));
    #pragma unroll
    for(int fr = 0; fr < 4; ++fr)
      #pragma unroll
      for(int fc = 0; fc < 4; ++fc)
        acc[fr][fc] = __builtin_amdgcn_mfma_f32_16x16x32_bf16(af[fr], bb[kc&3][fc], acc[fr][fc], 0, 0, 0);
    if(kc < 4){
      #pragma unroll
      for(int fc = 0; fc < 4; ++fc)
        bb[kc&3][fc] = *(const bf16x8*)(bp + fc*4096 + (kc+4)*32);
    }
  }
}

// LDS-staged GEMM (k_in_proj / k_out only, proven)
template<int KCH>
__device__ __forceinline__ void gemm_64x256(const unsigned short* __restrict__ wb,
                                            char* As, char* Bs,
                                            f32x4 (&acc)[4][4], int tid)
{
  const int lane = tid & 63;
  const int c0   = (tid >> 6) * 64;
  const int lr   = lane & 15;
  const int lk16 = (lane >> 4) * 16;
  #pragma unroll
  for(int kc = 0; kc < KCH; ++kc){
    __syncthreads();
    {
      const unsigned short* src = wb + (size_t)tid * (KCH*64) + kc*64;
      #pragma unroll
      for(int i = 0; i < 8; ++i){
        short8 v = *(const short8*)(src + i*8);
        *(short8*)(Bs + swzB(tid, i*16)) = v;
      }
    }
    __syncthreads();
    #pragma unroll
    for(int t2 = 0; t2 < 2; ++t2){
      bf16x8 af[4], bfr[4];
      #pragma unroll
      for(int fr = 0; fr < 4; ++fr)
        af[fr] = *(const bf16x8*)(As + swzA(fr*16 + lr, kc*128 + t2*64 + lk16));
      #pragma unroll
      for(int fc = 0; fc < 4; ++fc)
        bfr[fc] = *(const bf16x8*)(Bs + swzB(c0 + fc*16 + lr, t2*64 + lk16));
      #pragma unroll
      for(int fr = 0; fr < 4; ++fr)
        #pragma unroll
        for(int fc = 0; fc < 4; ++fc)
          acc[fr][fc] = __builtin_amdgcn_mfma_f32_16x16x32_bf16(af[fr], bfr[fc], acc[fr][fc], 0, 0, 0);
    }
  }
}

// ---------------- prep kernels ----------------
__global__ void k_cvt(const float* __restrict__ s, unsigned short* __restrict__ d, int n){
  int i = blockIdx.x*256 + threadIdx.x;
  if(i < n) d[i] = f2bf(s[i]);
}
__global__ void k_cvt_inw(const float* __restrict__ w, unsigned short* __restrict__ d){
  int i = blockIdx.x*256 + threadIdx.x;
  int n = i >> 7, f = i & 127;
  d[i] = (f < 96) ? f2bf(w[n*96 + f]) : (unsigned short)0;
}
__global__ void k_spT(const float* __restrict__ spw, unsigned short* __restrict__ d){
  int l = blockIdx.y;
  int i = blockIdx.x*256 + threadIdx.x;
  int dd = i >> 8, ss = i & 255;
  d[l*65536 + i] = f2bf(spw[l*65536 + ss*256 + dd]);
}
__global__ void k_decay(const float* __restrict__ A_log, float* __restrict__ decay){
  __shared__ float red[4];
  const int b = blockIdx.x;            // l*256 + d
  const int tid = threadIdx.x;
  float v = expf(A_log[(size_t)b*256 + tid]);
  #pragma unroll
  for(int o = 32; o >= 1; o >>= 1) v += __shfl_xor(v, o);
  if((tid & 63) == 0) red[tid >> 6] = v;
  __syncthreads();
  if(tid == 0){
    float s = red[0] + red[1] + red[2] + red[3];
    decay[b] = expf(-s * (1.f/256.f));
  }
}

// ---------------- h = gelu(LN(x @ in_w^T + in_b)) -> bf16 (v5 verbatim) ----------------
__global__ __launch_bounds__(256) void k_in_proj(
    const float* __restrict__ x_g,
    const unsigned short* __restrict__ in_wb,
    const float* __restrict__ in_b,
    const float* __restrict__ ln_gv, const float* __restrict__ ln_bv,
    unsigned short* __restrict__ h_g)
{
  __shared__ char smem[65536];
  char* As = smem; char* Bs = smem + 32768;
  const int tid = threadIdx.x;
  const int m0 = blockIdx.x * 64;
  const int lane = tid & 63, c0w = (tid>>6)*64, lr = lane & 15, rb = (lane>>4)*4;
  {
    const int r = tid >> 2, cq = tid & 3;
    const float* src = x_g + (size_t)(m0 + r)*FIN + cq*24;
    unsigned short tmp[24] __attribute__((aligned(16)));
    #pragma unroll
    for(int i = 0; i < 6; ++i){
      float4 v = *(const float4*)(src + i*4);
      tmp[4*i]=f2bf(v.x); tmp[4*i+1]=f2bf(v.y); tmp[4*i+2]=f2bf(v.z); tmp[4*i+3]=f2bf(v.w);
    }
    #pragma unroll
    for(int i = 0; i < 3; ++i)
      *(short8*)(As + swzA(r, cq*48 + i*16)) = *(const short8*)(tmp + i*8);
    if(cq == 3){
      short8 z8 = {0,0,0,0,0,0,0,0};
      #pragma unroll
      for(int i = 0; i < 4; ++i)
        *(short8*)(As + swzA(r, 192 + i*16)) = z8;
    }
  }
  f32x4 acc[4][4]; zero_acc(acc);
  gemm_64x256<2>(in_wb, As, Bs, acc, tid);
  __syncthreads();
  #pragma unroll
  for(int fc = 0; fc < 4; ++fc){
    const int col = c0w + fc*16 + lr;
    const float bb = in_b[col];
    #pragma unroll
    for(int fr = 0; fr < 4; ++fr)
      #pragma unroll
      for(int rg = 0; rg < 4; ++rg){
        const int row = fr*16 + rb + rg;
        *(float*)(smem + (((unsigned)(row*1024 + col*4)) ^ ((row&7)<<4))) = acc[fr][fc][rg] + bb;
      }
  }
  __syncthreads();
  {
    const int r = tid >> 2, c0 = (tid & 3) * 64;
    float vals[64]; float sm = 0.f, sq = 0.f;
    #pragma unroll
    for(int i = 0; i < 16; ++i){
      float4 v = *(const float4*)(smem + (((unsigned)(r*1024 + (c0 + i*4)*4)) ^ ((r&7)<<4)));
      vals[4*i]=v.x; vals[4*i+1]=v.y; vals[4*i+2]=v.z; vals[4*i+3]=v.w;
    }
    #pragma unroll
    for(int i = 0; i < 64; ++i){ sm += vals[i]; sq += vals[i]*vals[i]; }
    sm += __shfl_xor(sm, 1); sm += __shfl_xor(sm, 2);
    sq += __shfl_xor(sq, 1); sq += __shfl_xor(sq, 2);
    const float mu = sm * (1.f/256.f);
    const float rstd = rsqrtf(sq * (1.f/256.f) - mu*mu + 1e-5f);
    unsigned short* dst = h_g + (size_t)(m0 + r)*DMODEL + c0;
    #pragma unroll
    for(int i = 0; i < 8; ++i){
      float g[8];
      #pragma unroll
      for(int j = 0; j < 8; ++j){
        const int c = c0 + i*8 + j;
        g[j] = gelu_f((vals[i*8+j]-mu)*rstd*ln_gv[c] + ln_bv[c]);
      }
      u32x4 o;
      o[0] = pk_bf16(g[0],g[1]); o[1] = pk_bf16(g[2],g[3]);
      o[2] = pk_bf16(g[4],g[5]); o[3] = pk_bf16(g[6],g[7]);
      *(u32x4*)(dst + i*8) = o;
    }
  }
}

// ---------------- full layer: block = sequence, 8 serial tiles, exact scan ----------------
__global__ __launch_bounds__(256,2) void k_layer(
    unsigned short* __restrict__ h_g,
    const unsigned short* __restrict__ gate_wb,
    const unsigned short* __restrict__ sp_wb,
    const unsigned short* __restrict__ spT_wb,
    const unsigned short* __restrict__ op_wb,
    const float* __restrict__ ln_gv, const float* __restrict__ ln_bv,
    const float* __restrict__ gate_bv, const float* __restrict__ sp_bv,
    const float* __restrict__ decay_v, const float* __restrict__ D_v,
    const float* __restrict__ op_bv,
    float* __restrict__ state_buf, const int layer)
{
  __shared__ char As[32768];
  __shared__ char Ss[32768];
  const int tid = threadIdx.x;
  const int n = blockIdx.x;
  const int lane = tid & 63, c0w = (tid>>6)*64, lr = lane & 15, rb = (lane>>4)*4;
  const float dc = decay_v[tid];
  float st = (layer > 0) ? state_buf[n*256 + tid] : 0.f;

  #pragma unroll 1
  for(int kb = 0; kb < 8; ++kb){
    const int m0 = n*KSEQ + kb*64;
    // ---- Phase A: LN(h) -> z bf16 in As ----
    {
      const int r = tid >> 2, c0 = (tid & 3) * 64;
      const unsigned short* src = h_g + (size_t)(m0 + r)*DMODEL + c0;
      short8 hv[8];
      #pragma unroll
      for(int i = 0; i < 8; ++i) hv[i] = *(const short8*)(src + i*8);
      float sm = 0.f, sq = 0.f;
      #pragma unroll
      for(int i = 0; i < 8; ++i)
        #pragma unroll
        for(int j = 0; j < 8; ++j){
          float v = bf2f((unsigned short)hv[i][j]); sm += v; sq += v*v;
        }
      sm += __shfl_xor(sm, 1); sm += __shfl_xor(sm, 2);
      sq += __shfl_xor(sq, 1); sq += __shfl_xor(sq, 2);
      const float mu = sm * (1.f/256.f);
      const float rstd = rsqrtf(sq * (1.f/256.f) - mu*mu + 1e-5f);
      #pragma unroll
      for(int i = 0; i < 8; ++i){
        float z[8];
        #pragma unroll
        for(int j = 0; j < 8; ++j){
          const int c = c0 + i*8 + j;
          z[j] = (bf2f((unsigned short)hv[i][j])-mu)*rstd*ln_gv[c] + ln_bv[c];
        }
        u32x4 zz;
        zz[0] = pk_bf16(z[0],z[1]); zz[1] = pk_bf16(z[2],z[3]);
        zz[2] = pk_bf16(z[4],z[5]); zz[3] = pk_bf16(z[6],z[7]);
        *(u32x4*)(As + swzA(r, c0*2 + i*16)) = zz;
      }
    }
    __syncthreads();                                   // S1
    f32x4 acc[4][4]; zero_acc(acc);
    gemm_waveB(gate_wb, As, acc, lane, c0w);
    // xg = silu(acc+gb) -> Ss (persists until y-epilogue)
    #pragma unroll
    for(int fc = 0; fc < 4; ++fc){
      const int col = c0w + fc*16 + lr;
      const float gb = gate_bv[col];
      #pragma unroll
      for(int fr = 0; fr < 4; ++fr){
        const int row = fr*16 + rb;
        float v0 = silu_f(acc[fr][fc][0] + gb), v1 = silu_f(acc[fr][fc][1] + gb);
        float v2 = silu_f(acc[fr][fc][2] + gb), v3 = silu_f(acc[fr][fc][3] + gb);
        unsigned p0 = pk_bf16(v0, v1), p1 = pk_bf16(v2, v3);
        *(unsigned short*)(Ss + swzA(row+0, col*2)) = (unsigned short)p0;
        *(unsigned short*)(Ss + swzA(row+1, col*2)) = (unsigned short)(p0 >> 16);
        *(unsigned short*)(Ss + swzA(row+2, col*2)) = (unsigned short)p1;
        *(unsigned short*)(Ss + swzA(row+3, col*2)) = (unsigned short)(p1 >> 16);
      }
    }
    __syncthreads();                                   // S2
    zero_acc(acc);
    gemm_waveB(sp_wb, Ss, acc, lane, c0w);
    // s = acc + sp_b -> As
    #pragma unroll
    for(int fc = 0; fc < 4; ++fc){
      const int col = c0w + fc*16 + lr;
      const float sb = sp_bv[col];
      #pragma unroll
      for(int fr = 0; fr < 4; ++fr){
        const int row = fr*16 + rb;
        unsigned p0 = pk_bf16(acc[fr][fc][0] + sb, acc[fr][fc][1] + sb);
        unsigned p1 = pk_bf16(acc[fr][fc][2] + sb, acc[fr][fc][3] + sb);
        *(unsigned short*)(As + swzA(row+0, col*2)) = (unsigned short)p0;
        *(unsigned short*)(As + swzA(row+1, col*2)) = (unsigned short)(p0 >> 16);
        *(unsigned short*)(As + swzA(row+2, col*2)) = (unsigned short)p1;
        *(unsigned short*)(As + swzA(row+3, col*2)) = (unsigned short)(p1 >> 16);
      }
    }
    __syncthreads();                                   // S3
    // ---- scan (thread = channel), chunked 16 ----
    #pragma unroll
    for(int c4 = 0; c4 < 4; ++c4){
      const int base = c4*16;
      float v[16];
      #pragma unroll
      for(int j = 0; j < 16; ++j)
        v[j] = bf2f(*(const unsigned short*)(As + swzA(base+j, tid*2)));
      #pragma unroll
      for(int j = 0; j < 16; ++j){ st = st*dc + v[j]; v[j] = st; }
      #pragma unroll
      for(int j = 0; j < 8; ++j){
        unsigned p = pk_bf16(v[2*j], v[2*j+1]);
        *(unsigned short*)(As + swzA(base+2*j,   tid*2)) = (unsigned short)p;
        *(unsigned short*)(As + swzA(base+2*j+1, tid*2)) = (unsigned short)(p >> 16);
      }
    }
    __syncthreads();                                   // S4
    zero_acc(acc);
    gemm_waveB(spT_wb, As, acc, lane, c0w);            // y1 = states@sp_w
    __syncthreads();                                   // S5
    // y = acc + D*xg (xg from Ss) -> As
    #pragma unroll
    for(int fc = 0; fc < 4; ++fc){
      const int col = c0w + fc*16 + lr;
      const float Dv = D_v[col];
      #pragma unroll
      for(int fr = 0; fr < 4; ++fr){
        const int row = fr*16 + rb;
        float y0 = acc[fr][fc][0] + Dv*bf2f(*(const unsigned short*)(Ss + swzA(row+0, col*2)));
        float y1 = acc[fr][fc][1] + Dv*bf2f(*(const unsigned short*)(Ss + swzA(row+1, col*2)));
        float y2 = acc[fr][fc][2] + Dv*bf2f(*(const unsigned short*)(Ss + swzA(row+2, col*2)));
        float y3 = acc[fr][fc][3] + Dv*bf2f(*(const unsigned short*)(Ss + swzA(row+3, col*2)));
        unsigned p0 = pk_bf16(y0, y1), p1 = pk_bf16(y2, y3);
        *(unsigned short*)(As + swzA(row+0, col*2)) = (unsigned short)p0;
        *(unsigned short*)(As + swzA(row+1, col*2)) = (unsigned short)(p0 >> 16);
        *(unsigned short*)(As + swzA(row+2, col*2)) = (unsigned short)p1;
        *(unsigned short*)(As + swzA(row+3, col*2)) = (unsigned short)(p1 >> 16);
      }
    }
    __syncthreads();                                   // S6
    zero_acc(acc);
    gemm_waveB(op_wb, As, acc, lane, c0w);             // @op^T
    // acc + op_b -> Ss
    #pragma unroll
    for(int fc = 0; fc < 4; ++fc){
      const int col = c0w + fc*16 + lr;
      const float ob = op_bv[col];
      #pragma unroll
      for(int fr = 0; fr < 4; ++fr){
        const int row = fr*16 + rb;
        unsigned p0 = pk_bf16(acc[fr][fc][0] + ob, acc[fr][fc][1] + ob);
        unsigned p1 = pk_bf16(acc[fr][fc][2] + ob, acc[fr][fc][3] + ob);
        *(unsigned short*)(Ss + swzA(row+0, col*2)) = (unsigned short)p0;
        *(unsigned short*)(Ss + swzA(row+1, col*2)) = (unsigned short)(p0 >> 16);
        *(unsigned short*)(Ss + swzA(row+2, col*2)) = (unsigned short)p1;
        *(unsigned short*)(Ss + swzA(row+3, col*2)) = (unsigned short)(p1 >> 16);
      }
    }
    __syncthreads();                                   // S7
    // h += (y@op^T + op_b): cached reads (lines L2-hot from Phase A),
    // NONTEMPORAL store (coalesced full sectors; line not re-read in-kernel)
    {
      char* dst = (char*)(h_g + (size_t)m0*DMODEL);
      #pragma unroll
      for(int i = 0; i < 8; ++i){
        const unsigned flat = (unsigned)(i*4096 + tid*16);
        const unsigned row = flat >> 9;
        short8 a = *(const short8*)(Ss + (flat ^ ((row & 7u) << 4)));
        short8 hv = *(const short8*)(dst + flat);
        u32x4 o;
        #pragma unroll
        for(int j = 0; j < 4; ++j){
          float s0 = bf2f((unsigned short)a[2*j])   + bf2f((unsigned short)hv[2*j]);
          float s1 = bf2f((unsigned short)a[2*j+1]) + bf2f((unsigned short)hv[2*j+1]);
          o[j] = pk_bf16(s0, s1);
        }
        __builtin_nontemporal_store(o, (u32x4*)(dst + flat));
      }
    }
    // next tile's Phase A writes As (all As reads drained at S7)
  }
  state_buf[n*256 + tid] = st;
}

// ---------------- out = gelu(LN(h[:,511,:] @ out_w^T + out_b)) (v5 verbatim) ----------------
__global__ __launch_bounds__(256) void k_out(
    const unsigned short* __restrict__ h_g,
    const unsigned short* __restrict__ out_wb,
    const float* __restrict__ out_bv,
    const float* __restrict__ ln_gv, const float* __restrict__ ln_bv,
    float* __restrict__ out_g)
{
  __shared__ char smem[65536];
  char* As = smem; char* Bs = smem + 32768;
  const int tid = threadIdx.x;
  const int r0 = blockIdx.x * 64;
  const int lane = tid & 63, c0w = (tid>>6)*64, lr = lane & 15, rb = (lane>>4)*4;
  {
    const int r = tid >> 2, c0 = (tid & 3) * 64;
    const unsigned short* src = h_g + ((size_t)(r0 + r)*KSEQ + (KSEQ-1))*DMODEL + c0;
    #pragma unroll
    for(int i = 0; i < 8; ++i){
      short8 v = *(const short8*)(src + i*8);
      *(short8*)(As + swzA(r, c0*2 + i*16)) = v;
    }
  }
  f32x4 acc[4][4]; zero_acc(acc);
  gemm_64x256<4>(out_wb, As, Bs, acc, tid);
  __syncthreads();
  #pragma unroll
  for(int fc = 0; fc < 4; ++fc){
    const int col = c0w + fc*16 + lr;
    const float bb = out_bv[col];
    #pragma unroll
    for(int fr = 0; fr < 4; ++fr)
      #pragma unroll
      for(int rg = 0; rg < 4; ++rg){
        const int row = fr*16 + rb + rg;
        *(float*)(smem + (((unsigned)(row*1024 + col*4)) ^ ((row&7)<<4))) = acc[fr][fc][rg] + bb;
      }
  }
  __syncthreads();
  {
    const int r = tid >> 2, c0 = (tid & 3) * 64;
    float vals[64]; float sm = 0.f, sq = 0.f;
    #pragma unroll
    for(int i = 0; i < 16; ++i){
      float4 v = *(const float4*)(smem + (((unsigned)(r*1024 + (c0 + i*4)*4)) ^ ((r&7)<<4)));
      vals[4*i]=v.x; vals[4*i+1]=v.y; vals[4*i+2]=v.z; vals[4*i+3]=v.w;
    }
    #pragma unroll
    for(int i = 0; i < 64; ++i){ sm += vals[i]; sq += vals[i]*vals[i]; }
    sm += __shfl_xor(sm, 1); sm += __shfl_xor(sm, 2);
    sq += __shfl_xor(sq, 1); sq += __shfl_xor(sq, 2);
    const float mu = sm * (1.f/256.f);
    const float rstd = rsqrtf(sq * (1.f/256.f) - mu*mu + 1e-5f);
    float* dst = out_g + (size_t)(r0 + r)*DMODEL + c0;
    #pragma unroll
    for(int i = 0; i < 16; ++i){
      float4 o;
      o.x = gelu_f((vals[4*i+0]-mu)*rstd*ln_gv[c0+i*4+0] + ln_bv[c0+i*4+0]);
      o.y = gelu_f((vals[4*i+1]-mu)*rstd*ln_gv[c0+i*4+1] + ln_bv[c0+i*4+1]);
      o.z = gelu_f((vals[4*i+2]-mu)*rstd*ln_gv[c0+i*4+2] + ln_bv[c0+i*4+2]);
      o.w = gelu_f((vals[4*i+3]-mu)*rstd*ln_gv[c0+i*4+3] + ln_bv[c0+i*4+3]);
      *(float4*)(dst + i*4) = o;
    }
  }
}

extern "C" void kernel_launch(void* const* d_in, const int* in_sizes, int n_in,
                              void* d_out, int out_size, void* d_ws, size_t ws_size,
                              hipStream_t stream) {
  (void)in_sizes; (void)n_in; (void)out_size; (void)ws_size;
  const float* x        = (const float*)d_in[0];
  const float* in_w     = (const float*)d_in[1];
  const float* in_b     = (const float*)d_in[2];
  const float* in_ln_g  = (const float*)d_in[3];
  const float* in_ln_b  = (const float*)d_in[4];
  const float* ln_g     = (const float*)d_in[5];
  const float* ln_b     = (const float*)d_in[6];
  const float* gate_w   = (const float*)d_in[7];
  const float* gate_b   = (const float*)d_in[8];
  const float* sp_w     = (const float*)d_in[9];
  const float* sp_b     = (const float*)d_in[10];
  const float* op_w     = (const float*)d_in[11];
  const float* op_b     = (const float*)d_in[12];
  const float* A_log    = (const float*)d_in[13];
  const float* Dp       = (const float*)d_in[14];
  const float* out_w    = (const float*)d_in[15];
  const float* out_b    = (const float*)d_in[16];
  const float* out_ln_g = (const float*)d_in[17];
  const float* out_ln_b = (const float*)d_in[18];

  char* ws = (char*)d_ws;
  // ~133.7 MiB workspace (proven budget)
  unsigned short* h_g       = (unsigned short*)(ws + 0);           // 128 MiB
  float*          state_buf = (float*)(ws + 134217728);            // 512 KiB
  float*          decay     = (float*)(ws + 134742016);            // 2 KiB
  unsigned short* wbase     = (unsigned short*)(ws + 134744064);   // ~1.2 MiB
  unsigned short* in_wb  = wbase;               // 32768
  unsigned short* gate_wb= in_wb  + 32768;      // 2*65536
  unsigned short* sp_wb  = gate_wb+ 131072;
  unsigned short* sp_wTb = sp_wb  + 131072;
  unsigned short* op_wb  = sp_wTb + 131072;
  unsigned short* out_wb = op_wb  + 131072;     // 65536

  // prep
  k_cvt_inw<<<128, 256, 0, stream>>>(in_w, in_wb);
  k_cvt<<<512, 256, 0, stream>>>(gate_w, gate_wb, 131072);
  k_cvt<<<512, 256, 0, stream>>>(sp_w,   sp_wb,   131072);
  k_cvt<<<512, 256, 0, stream>>>(op_w,   op_wb,   131072);
  k_cvt<<<256, 256, 0, stream>>>(out_w,  out_wb,  65536);
  k_spT<<<dim3(256,2), 256, 0, stream>>>(sp_w, sp_wTb);
  k_decay<<<512, 256, 0, stream>>>(A_log, decay);

  // pipeline
  k_in_proj<<<MTOT/64, 256, 0, stream>>>(x, in_wb, in_b, in_ln_g, in_ln_b, h_g);
  for(int l = 0; l < 2; ++l){
    k_layer<<<NSEQ, 256, 0, stream>>>(h_g,
        gate_wb + l*65536, sp_wb + l*65536, sp_wTb + l*65536, op_wb + l*65536,
        ln_g + l*256, ln_b + l*256, gate_b + l*256, sp_b + l*256,
        decay + l*256, Dp + l*256, op_b + l*256, state_buf, l);
  }
  k_out<<<NSEQ/64, 256, 0, stream>>>(h_g, out_wb, out_b, out_ln_g, out_ln_b, (float*)d_out);
}

// Round 10
// 1060.952 us; speedup vs baseline: 2.5223x; 1.2732x over previous
//
#include <hip/hip_runtime.h>
#include <hip/hip_bf16.h>

// MambaEncoder on MI355X — v10: occupancy attack.
//  (1) layer kernel at 512 threads / 8 waves (wave owns 32 output cols):
//      16 waves/CU = 4/SIMD (was 2/SIMD) -> 2x latency-hiding.
//  (2) BOTH layers in one kernel (block = sequence): scan state carries
//      in-register across layers (matches reference semantics); state_buf
//      and one launch eliminated; inter-layer h stays cache-warm.
//  Per tile: 7 barriers, As/Ss 32KB, exact reg-carried scan (tid<256),
//  waveB GEMMs with 4-deep B-chunk ring. ws ~133.7MiB.

typedef __attribute__((ext_vector_type(8))) __bf16 bf16x8;
typedef __attribute__((ext_vector_type(8))) short short8;
typedef __attribute__((ext_vector_type(4))) float f32x4;
typedef __attribute__((ext_vector_type(4))) unsigned u32x4;

#define NSEQ 512
#define KSEQ 512
#define FIN 96
#define DMODEL 256
#define MTOT (NSEQ*KSEQ)

__device__ __forceinline__ unsigned short f2bf(float f){
  union { float f; unsigned u; } v; v.f = f;
  unsigned r = (v.u + 0x7FFFu + ((v.u >> 16) & 1u)) >> 16;
  return (unsigned short)r;
}
__device__ __forceinline__ float bf2f(unsigned short b){
  union { unsigned u; float f; } v; v.u = ((unsigned)b) << 16; return v.f;
}
__device__ __forceinline__ unsigned pk_bf16(float lo, float hi){
  unsigned r;
  asm("v_cvt_pk_bf16_f32 %0, %1, %2" : "=v"(r) : "v"(lo), "v"(hi));
  return r;
}
__device__ __forceinline__ float gelu_f(float x){
  return 0.5f * x * (1.0f + erff(x * 0.70710678118654752440f));
}
__device__ __forceinline__ float silu_f(float x){
  return x / (1.0f + __expf(-x));
}
__device__ __forceinline__ unsigned swzA(int row, int kbyte){   // [64][256] bf16, 512B stride
  return ((unsigned)(row*512 + kbyte)) ^ (unsigned)((row & 7) << 4);
}
__device__ __forceinline__ unsigned swzB(int n, int kbyte){     // [256][64] bf16
  return ((unsigned)(n*128 + kbyte)) ^ (unsigned)((n & 7) << 4);
}

// 8-wave per-wave GEMM: acc[4][2] += A(64x256 LDS, swzA) @ W[cols c0..c0+32]^T
// B direct from global, 4-deep chunk prefetch ring.
__device__ __forceinline__ void gemm_w8(const unsigned short* __restrict__ wb,
                                        const char* As, f32x4 (&acc)[4][2],
                                        int lane, int c0)
{
  const int lr  = lane & 15;
  const int lk8 = (lane >> 4) * 8;
  const unsigned short* bp = wb + (size_t)(c0 + lr)*256 + lk8;   // +fc*4096 +kc*32
  bf16x8 bb[4][2];
  #pragma unroll
  for(int p = 0; p < 4; ++p)
    #pragma unroll
    for(int fc = 0; fc < 2; ++fc)
      bb[p][fc] = *(const bf16x8*)(bp + fc*4096 + p*32);
  #pragma unroll
  for(int kc = 0; kc < 8; ++kc){
    bf16x8 af[4];
    #pragma unroll
    for(int fr = 0; fr < 4; ++fr)
      af[fr] = *(const bf16x8*)(As + swzA(fr*16 + lr, kc*64 + lk8*2));
    #pragma unroll
    for(int fr = 0; fr < 4; ++fr)
      #pragma unroll
      for(int fc = 0; fc < 2; ++fc)
        acc[fr][fc] = __builtin_amdgcn_mfma_f32_16x16x32_bf16(af[fr], bb[kc&3][fc], acc[fr][fc], 0, 0, 0);
    if(kc < 4){
      #pragma unroll
      for(int fc = 0; fc < 2; ++fc)
        bb[kc&3][fc] = *(const bf16x8*)(bp + fc*4096 + (kc+4)*32);
    }
  }
}

__device__ __forceinline__ void zero_acc2(f32x4 (&acc)[4][2]){
  #pragma unroll
  for(int a=0;a<4;++a)
    #pragma unroll
    for(int b=0;b<2;++b)
      acc[a][b] = (f32x4){0.f,0.f,0.f,0.f};
}
__device__ __forceinline__ void zero_acc(f32x4 (&acc)[4][4]){
  #pragma unroll
  for(int a=0;a<4;++a)
    #pragma unroll
    for(int b=0;b<4;++b)
      acc[a][b] = (f32x4){0.f,0.f,0.f,0.f};
}

// LDS-staged GEMM (k_in_proj / k_out only, proven, 256 thr)
template<int KCH>
__device__ __forceinline__ void gemm_64x256(const unsigned short* __restrict__ wb,
                                            char* As, char* Bs,
                                            f32x4 (&acc)[4][4], int tid)
{
  const int lane = tid & 63;
  const int c0   = (tid >> 6) * 64;
  const int lr   = lane & 15;
  const int lk16 = (lane >> 4) * 16;
  #pragma unroll
  for(int kc = 0; kc < KCH; ++kc){
    __syncthreads();
    {
      const unsigned short* src = wb + (size_t)tid * (KCH*64) + kc*64;
      #pragma unroll
      for(int i = 0; i < 8; ++i){
        short8 v = *(const short8*)(src + i*8);
        *(short8*)(Bs + swzB(tid, i*16)) = v;
      }
    }
    __syncthreads();
    #pragma unroll
    for(int t2 = 0; t2 < 2; ++t2){
      bf16x8 af[4], bfr[4];
      #pragma unroll
      for(int fr = 0; fr < 4; ++fr)
        af[fr] = *(const bf16x8*)(As + swzA(fr*16 + lr, kc*128 + t2*64 + lk16));
      #pragma unroll
      for(int fc = 0; fc < 4; ++fc)
        bfr[fc] = *(const bf16x8*)(Bs + swzB(c0 + fc*16 + lr, t2*64 + lk16));
      #pragma unroll
      for(int fr = 0; fr < 4; ++fr)
        #pragma unroll
        for(int fc = 0; fc < 4; ++fc)
          acc[fr][fc] = __builtin_amdgcn_mfma_f32_16x16x32_bf16(af[fr], bfr[fc], acc[fr][fc], 0, 0, 0);
    }
  }
}

// ---------------- prep kernels ----------------
__global__ void k_cvt(const float* __restrict__ s, unsigned short* __restrict__ d, int n){
  int i = blockIdx.x*256 + threadIdx.x;
  if(i < n) d[i] = f2bf(s[i]);
}
__global__ void k_cvt_inw(const float* __restrict__ w, unsigned short* __restrict__ d){
  int i = blockIdx.x*256 + threadIdx.x;
  int n = i >> 7, f = i & 127;
  d[i] = (f < 96) ? f2bf(w[n*96 + f]) : (unsigned short)0;
}
__global__ void k_spT(const float* __restrict__ spw, unsigned short* __restrict__ d){
  int l = blockIdx.y;
  int i = blockIdx.x*256 + threadIdx.x;
  int dd = i >> 8, ss = i & 255;
  d[l*65536 + i] = f2bf(spw[l*65536 + ss*256 + dd]);
}
__global__ void k_decay(const float* __restrict__ A_log, float* __restrict__ decay){
  __shared__ float red[4];
  const int b = blockIdx.x;            // l*256 + d
  const int tid = threadIdx.x;
  float v = expf(A_log[(size_t)b*256 + tid]);
  #pragma unroll
  for(int o = 32; o >= 1; o >>= 1) v += __shfl_xor(v, o);
  if((tid & 63) == 0) red[tid >> 6] = v;
  __syncthreads();
  if(tid == 0){
    float s = red[0] + red[1] + red[2] + red[3];
    decay[b] = expf(-s * (1.f/256.f));
  }
}

// ---------------- h = gelu(LN(x @ in_w^T + in_b)) -> bf16 (proven) ----------------
__global__ __launch_bounds__(256) void k_in_proj(
    const float* __restrict__ x_g,
    const unsigned short* __restrict__ in_wb,
    const float* __restrict__ in_b,
    const float* __restrict__ ln_gv, const float* __restrict__ ln_bv,
    unsigned short* __restrict__ h_g)
{
  __shared__ char smem[65536];
  char* As = smem; char* Bs = smem + 32768;
  const int tid = threadIdx.x;
  const int m0 = blockIdx.x * 64;
  const int lane = tid & 63, c0w = (tid>>6)*64, lr = lane & 15, rb = (lane>>4)*4;
  {
    const int r = tid >> 2, cq = tid & 3;
    const float* src = x_g + (size_t)(m0 + r)*FIN + cq*24;
    unsigned short tmp[24] __attribute__((aligned(16)));
    #pragma unroll
    for(int i = 0; i < 6; ++i){
      float4 v = *(const float4*)(src + i*4);
      tmp[4*i]=f2bf(v.x); tmp[4*i+1]=f2bf(v.y); tmp[4*i+2]=f2bf(v.z); tmp[4*i+3]=f2bf(v.w);
    }
    #pragma unroll
    for(int i = 0; i < 3; ++i)
      *(short8*)(As + swzA(r, cq*48 + i*16)) = *(const short8*)(tmp + i*8);
    if(cq == 3){
      short8 z8 = {0,0,0,0,0,0,0,0};
      #pragma unroll
      for(int i = 0; i < 4; ++i)
        *(short8*)(As + swzA(r, 192 + i*16)) = z8;
    }
  }
  f32x4 acc[4][4]; zero_acc(acc);
  gemm_64x256<2>(in_wb, As, Bs, acc, tid);
  __syncthreads();
  #pragma unroll
  for(int fc = 0; fc < 4; ++fc){
    const int col = c0w + fc*16 + lr;
    const float bb = in_b[col];
    #pragma unroll
    for(int fr = 0; fr < 4; ++fr)
      #pragma unroll
      for(int rg = 0; rg < 4; ++rg){
        const int row = fr*16 + rb + rg;
        *(float*)(smem + (((unsigned)(row*1024 + col*4)) ^ ((row&7)<<4))) = acc[fr][fc][rg] + bb;
      }
  }
  __syncthreads();
  {
    const int r = tid >> 2, c0 = (tid & 3) * 64;
    float vals[64]; float sm = 0.f, sq = 0.f;
    #pragma unroll
    for(int i = 0; i < 16; ++i){
      float4 v = *(const float4*)(smem + (((unsigned)(r*1024 + (c0 + i*4)*4)) ^ ((r&7)<<4)));
      vals[4*i]=v.x; vals[4*i+1]=v.y; vals[4*i+2]=v.z; vals[4*i+3]=v.w;
    }
    #pragma unroll
    for(int i = 0; i < 64; ++i){ sm += vals[i]; sq += vals[i]*vals[i]; }
    sm += __shfl_xor(sm, 1); sm += __shfl_xor(sm, 2);
    sq += __shfl_xor(sq, 1); sq += __shfl_xor(sq, 2);
    const float mu = sm * (1.f/256.f);
    const float rstd = rsqrtf(sq * (1.f/256.f) - mu*mu + 1e-5f);
    unsigned short* dst = h_g + (size_t)(m0 + r)*DMODEL + c0;
    #pragma unroll
    for(int i = 0; i < 8; ++i){
      float g[8];
      #pragma unroll
      for(int j = 0; j < 8; ++j){
        const int c = c0 + i*8 + j;
        g[j] = gelu_f((vals[i*8+j]-mu)*rstd*ln_gv[c] + ln_bv[c]);
      }
      u32x4 o;
      o[0] = pk_bf16(g[0],g[1]); o[1] = pk_bf16(g[2],g[3]);
      o[2] = pk_bf16(g[4],g[5]); o[3] = pk_bf16(g[6],g[7]);
      *(u32x4*)(dst + i*8) = o;
    }
  }
}

// ---------------- BOTH layers: block = sequence, 512 thr / 8 waves ----------------
__global__ __launch_bounds__(512,2) void k_layers(
    unsigned short* __restrict__ h_g,
    const unsigned short* __restrict__ gate_w0,
    const unsigned short* __restrict__ sp_w0,
    const unsigned short* __restrict__ spT_w0,
    const unsigned short* __restrict__ op_w0,
    const float* __restrict__ ln_g0, const float* __restrict__ ln_b0,
    const float* __restrict__ gate_b0, const float* __restrict__ sp_b0,
    const float* __restrict__ decay0, const float* __restrict__ D0,
    const float* __restrict__ op_b0)
{
  __shared__ char As[32768];
  __shared__ char Ss[32768];
  const int tid = threadIdx.x;
  const int n = blockIdx.x;
  const int lane = tid & 63;
  const int c0w = (tid >> 6) * 32;            // wave -> 32 output cols
  const int lr = lane & 15, rb = (lane>>4)*4;
  const int rA = tid >> 3, cAh = (tid & 7) * 32;   // LN: 8 thr/row, 32 vals
  float st = 0.f;                              // scan state, carried across layers

  #pragma unroll 1
  for(int l = 0; l < 2; ++l){
    const unsigned short* gw  = gate_w0 + l*65536;
    const unsigned short* spw = sp_w0   + l*65536;
    const unsigned short* spT = spT_w0  + l*65536;
    const unsigned short* opw = op_w0   + l*65536;
    const float* lg  = ln_g0   + l*256;
    const float* lb  = ln_b0   + l*256;
    const float* gb_ = gate_b0 + l*256;
    const float* sb_ = sp_b0   + l*256;
    const float* Dv_ = D0      + l*256;
    const float* ob_ = op_b0   + l*256;
    const float dc = decay0[l*256 + (tid & 255)];

    #pragma unroll 1
    for(int kb = 0; kb < 8; ++kb){
      const int m0 = n*KSEQ + kb*64;
      // ---- Phase A: LN(h) -> z bf16 in As (8 thr/row) ----
      {
        const unsigned short* src = h_g + (size_t)(m0 + rA)*DMODEL + cAh;
        short8 hv[4];
        #pragma unroll
        for(int i = 0; i < 4; ++i) hv[i] = *(const short8*)(src + i*8);
        float sm = 0.f, sq = 0.f;
        #pragma unroll
        for(int i = 0; i < 4; ++i)
          #pragma unroll
          for(int j = 0; j < 8; ++j){
            float v = bf2f((unsigned short)hv[i][j]); sm += v; sq += v*v;
          }
        sm += __shfl_xor(sm, 1); sm += __shfl_xor(sm, 2); sm += __shfl_xor(sm, 4);
        sq += __shfl_xor(sq, 1); sq += __shfl_xor(sq, 2); sq += __shfl_xor(sq, 4);
        const float mu = sm * (1.f/256.f);
        const float rstd = rsqrtf(sq * (1.f/256.f) - mu*mu + 1e-5f);
        #pragma unroll
        for(int i = 0; i < 4; ++i){
          float z[8];
          #pragma unroll
          for(int j = 0; j < 8; ++j){
            const int c = cAh + i*8 + j;
            z[j] = (bf2f((unsigned short)hv[i][j])-mu)*rstd*lg[c] + lb[c];
          }
          u32x4 zz;
          zz[0] = pk_bf16(z[0],z[1]); zz[1] = pk_bf16(z[2],z[3]);
          zz[2] = pk_bf16(z[4],z[5]); zz[3] = pk_bf16(z[6],z[7]);
          *(u32x4*)(As + swzA(rA, cAh*2 + i*16)) = zz;
        }
      }
      __syncthreads();                                 // S1
      f32x4 acc[4][2]; zero_acc2(acc);
      gemm_w8(gw, As, acc, lane, c0w);
      // xg = silu(acc+gb) -> Ss
      #pragma unroll
      for(int fc = 0; fc < 2; ++fc){
        const int col = c0w + fc*16 + lr;
        const float gb = gb_[col];
        #pragma unroll
        for(int fr = 0; fr < 4; ++fr){
          const int row = fr*16 + rb;
          float v0 = silu_f(acc[fr][fc][0] + gb), v1 = silu_f(acc[fr][fc][1] + gb);
          float v2 = silu_f(acc[fr][fc][2] + gb), v3 = silu_f(acc[fr][fc][3] + gb);
          unsigned p0 = pk_bf16(v0, v1), p1 = pk_bf16(v2, v3);
          *(unsigned short*)(Ss + swzA(row+0, col*2)) = (unsigned short)p0;
          *(unsigned short*)(Ss + swzA(row+1, col*2)) = (unsigned short)(p0 >> 16);
          *(unsigned short*)(Ss + swzA(row+2, col*2)) = (unsigned short)p1;
          *(unsigned short*)(Ss + swzA(row+3, col*2)) = (unsigned short)(p1 >> 16);
        }
      }
      __syncthreads();                                 // S2
      zero_acc2(acc);
      gemm_w8(spw, Ss, acc, lane, c0w);
      // s = acc + sp_b -> As
      #pragma unroll
      for(int fc = 0; fc < 2; ++fc){
        const int col = c0w + fc*16 + lr;
        const float sb = sb_[col];
        #pragma unroll
        for(int fr = 0; fr < 4; ++fr){
          const int row = fr*16 + rb;
          unsigned p0 = pk_bf16(acc[fr][fc][0] + sb, acc[fr][fc][1] + sb);
          unsigned p1 = pk_bf16(acc[fr][fc][2] + sb, acc[fr][fc][3] + sb);
          *(unsigned short*)(As + swzA(row+0, col*2)) = (unsigned short)p0;
          *(unsigned short*)(As + swzA(row+1, col*2)) = (unsigned short)(p0 >> 16);
          *(unsigned short*)(As + swzA(row+2, col*2)) = (unsigned short)p1;
          *(unsigned short*)(As + swzA(row+3, col*2)) = (unsigned short)(p1 >> 16);
        }
      }
      __syncthreads();                                 // S3
      // ---- scan (thread = channel, tid<256), chunked 16 ----
      if(tid < 256){
        #pragma unroll
        for(int c4 = 0; c4 < 4; ++c4){
          const int base = c4*16;
          float v[16];
          #pragma unroll
          for(int j = 0; j < 16; ++j)
            v[j] = bf2f(*(const unsigned short*)(As + swzA(base+j, tid*2)));
          #pragma unroll
          for(int j = 0; j < 16; ++j){ st = st*dc + v[j]; v[j] = st; }
          #pragma unroll
          for(int j = 0; j < 8; ++j){
            unsigned p = pk_bf16(v[2*j], v[2*j+1]);
            *(unsigned short*)(As + swzA(base+2*j,   tid*2)) = (unsigned short)p;
            *(unsigned short*)(As + swzA(base+2*j+1, tid*2)) = (unsigned short)(p >> 16);
          }
        }
      }
      __syncthreads();                                 // S4
      zero_acc2(acc);
      gemm_w8(spT, As, acc, lane, c0w);                // y1 = states@sp_w
      __syncthreads();                                 // S5
      // y = acc + D*xg (xg from Ss) -> As
      #pragma unroll
      for(int fc = 0; fc < 2; ++fc){
        const int col = c0w + fc*16 + lr;
        const float Dv = Dv_[col];
        #pragma unroll
        for(int fr = 0; fr < 4; ++fr){
          const int row = fr*16 + rb;
          float y0 = acc[fr][fc][0] + Dv*bf2f(*(const unsigned short*)(Ss + swzA(row+0, col*2)));
          float y1 = acc[fr][fc][1] + Dv*bf2f(*(const unsigned short*)(Ss + swzA(row+1, col*2)));
          float y2 = acc[fr][fc][2] + Dv*bf2f(*(const unsigned short*)(Ss + swzA(row+2, col*2)));
          float y3 = acc[fr][fc][3] + Dv*bf2f(*(const unsigned short*)(Ss + swzA(row+3, col*2)));
          unsigned p0 = pk_bf16(y0, y1), p1 = pk_bf16(y2, y3);
          *(unsigned short*)(As + swzA(row+0, col*2)) = (unsigned short)p0;
          *(unsigned short*)(As + swzA(row+1, col*2)) = (unsigned short)(p0 >> 16);
          *(unsigned short*)(As + swzA(row+2, col*2)) = (unsigned short)p1;
          *(unsigned short*)(As + swzA(row+3, col*2)) = (unsigned short)(p1 >> 16);
        }
      }
      __syncthreads();                                 // S6
      zero_acc2(acc);
      gemm_w8(opw, As, acc, lane, c0w);                // @op^T
      // acc + op_b -> Ss
      #pragma unroll
      for(int fc = 0; fc < 2; ++fc){
        const int col = c0w + fc*16 + lr;
        const float ob = ob_[col];
        #pragma unroll
        for(int fr = 0; fr < 4; ++fr){
          const int row = fr*16 + rb;
          unsigned p0 = pk_bf16(acc[fr][fc][0] + ob, acc[fr][fc][1] + ob);
          unsigned p1 = pk_bf16(acc[fr][fc][2] + ob, acc[fr][fc][3] + ob);
          *(unsigned short*)(Ss + swzA(row+0, col*2)) = (unsigned short)p0;
          *(unsigned short*)(Ss + swzA(row+1, col*2)) = (unsigned short)(p0 >> 16);
          *(unsigned short*)(Ss + swzA(row+2, col*2)) = (unsigned short)p1;
          *(unsigned short*)(Ss + swzA(row+3, col*2)) = (unsigned short)(p1 >> 16);
        }
      }
      __syncthreads();                                 // S7
      // h += (y@op^T + op_b), coalesced RMW from Ss (4 x 16B/thread)
      {
        char* dst = (char*)(h_g + (size_t)m0*DMODEL);
        #pragma unroll
        for(int i = 0; i < 4; ++i){
          const unsigned flat = (unsigned)(i*8192 + tid*16);
          const unsigned row = flat >> 9;
          short8 a = *(const short8*)(Ss + (flat ^ ((row & 7u) << 4)));
          short8 hv = *(const short8*)(dst + flat);
          u32x4 o;
          #pragma unroll
          for(int j = 0; j < 4; ++j){
            float s0 = bf2f((unsigned short)a[2*j])   + bf2f((unsigned short)hv[2*j]);
            float s1 = bf2f((unsigned short)a[2*j+1]) + bf2f((unsigned short)hv[2*j+1]);
            o[j] = pk_bf16(s0, s1);
          }
          *(u32x4*)(dst + flat) = o;
        }
      }
      // next Phase A writes As only after S7 (As reads done); Ss fenced by S1
    }
  }
}

// ---------------- out = gelu(LN(h[:,511,:] @ out_w^T + out_b)) (proven) ----------------
__global__ __launch_bounds__(256) void k_out(
    const unsigned short* __restrict__ h_g,
    const unsigned short* __restrict__ out_wb,
    const float* __restrict__ out_bv,
    const float* __restrict__ ln_gv, const float* __restrict__ ln_bv,
    float* __restrict__ out_g)
{
  __shared__ char smem[65536];
  char* As = smem; char* Bs = smem + 32768;
  const int tid = threadIdx.x;
  const int r0 = blockIdx.x * 64;
  const int lane = tid & 63, c0w = (tid>>6)*64, lr = lane & 15, rb = (lane>>4)*4;
  {
    const int r = tid >> 2, c0 = (tid & 3) * 64;
    const unsigned short* src = h_g + ((size_t)(r0 + r)*KSEQ + (KSEQ-1))*DMODEL + c0;
    #pragma unroll
    for(int i = 0; i < 8; ++i){
      short8 v = *(const short8*)(src + i*8);
      *(short8*)(As + swzA(r, c0*2 + i*16)) = v;
    }
  }
  f32x4 acc[4][4]; zero_acc(acc);
  gemm_64x256<4>(out_wb, As, Bs, acc, tid);
  __syncthreads();
  #pragma unroll
  for(int fc = 0; fc < 4; ++fc){
    const int col = c0w + fc*16 + lr;
    const float bb = out_bv[col];
    #pragma unroll
    for(int fr = 0; fr < 4; ++fr)
      #pragma unroll
      for(int rg = 0; rg < 4; ++rg){
        const int row = fr*16 + rb + rg;
        *(float*)(smem + (((unsigned)(row*1024 + col*4)) ^ ((row&7)<<4))) = acc[fr][fc][rg] + bb;
      }
  }
  __syncthreads();
  {
    const int r = tid >> 2, c0 = (tid & 3) * 64;
    float vals[64]; float sm = 0.f, sq = 0.f;
    #pragma unroll
    for(int i = 0; i < 16; ++i){
      float4 v = *(const float4*)(smem + (((unsigned)(r*1024 + (c0 + i*4)*4)) ^ ((r&7)<<4)));
      vals[4*i]=v.x; vals[4*i+1]=v.y; vals[4*i+2]=v.z; vals[4*i+3]=v.w;
    }
    #pragma unroll
    for(int i = 0; i < 64; ++i){ sm += vals[i]; sq += vals[i]*vals[i]; }
    sm += __shfl_xor(sm, 1); sm += __shfl_xor(sm, 2);
    sq += __shfl_xor(sq, 1); sq += __shfl_xor(sq, 2);
    const float mu = sm * (1.f/256.f);
    const float rstd = rsqrtf(sq * (1.f/256.f) - mu*mu + 1e-5f);
    float* dst = out_g + (size_t)(r0 + r)*DMODEL + c0;
    #pragma unroll
    for(int i = 0; i < 16; ++i){
      float4 o;
      o.x = gelu_f((vals[4*i+0]-mu)*rstd*ln_gv[c0+i*4+0] + ln_bv[c0+i*4+0]);
      o.y = gelu_f((vals[4*i+1]-mu)*rstd*ln_gv[c0+i*4+1] + ln_bv[c0+i*4+1]);
      o.z = gelu_f((vals[4*i+2]-mu)*rstd*ln_gv[c0+i*4+2] + ln_bv[c0+i*4+2]);
      o.w = gelu_f((vals[4*i+3]-mu)*rstd*ln_gv[c0+i*4+3] + ln_bv[c0+i*4+3]);
      *(float4*)(dst + i*4) = o;
    }
  }
}

extern "C" void kernel_launch(void* const* d_in, const int* in_sizes, int n_in,
                              void* d_out, int out_size, void* d_ws, size_t ws_size,
                              hipStream_t stream) {
  (void)in_sizes; (void)n_in; (void)out_size; (void)ws_size;
  const float* x        = (const float*)d_in[0];
  const float* in_w     = (const float*)d_in[1];
  const float* in_b     = (const float*)d_in[2];
  const float* in_ln_g  = (const float*)d_in[3];
  const float* in_ln_b  = (const float*)d_in[4];
  const float* ln_g     = (const float*)d_in[5];
  const float* ln_b     = (const float*)d_in[6];
  const float* gate_w   = (const float*)d_in[7];
  const float* gate_b   = (const float*)d_in[8];
  const float* sp_w     = (const float*)d_in[9];
  const float* sp_b     = (const float*)d_in[10];
  const float* op_w     = (const float*)d_in[11];
  const float* op_b     = (const float*)d_in[12];
  const float* A_log    = (const float*)d_in[13];
  const float* Dp       = (const float*)d_in[14];
  const float* out_w    = (const float*)d_in[15];
  const float* out_b    = (const float*)d_in[16];
  const float* out_ln_g = (const float*)d_in[17];
  const float* out_ln_b = (const float*)d_in[18];

  char* ws = (char*)d_ws;
  // ~133.7 MiB workspace (proven budget)
  unsigned short* h_g       = (unsigned short*)(ws + 0);           // 128 MiB
  float*          decay     = (float*)(ws + 134217728);            // 2 KiB
  unsigned short* wbase     = (unsigned short*)(ws + 134219776);   // ~1.2 MiB
  unsigned short* in_wb  = wbase;               // 32768
  unsigned short* gate_wb= in_wb  + 32768;      // 2*65536
  unsigned short* sp_wb  = gate_wb+ 131072;
  unsigned short* sp_wTb = sp_wb  + 131072;
  unsigned short* op_wb  = sp_wTb + 131072;
  unsigned short* out_wb = op_wb  + 131072;     // 65536

  // prep
  k_cvt_inw<<<128, 256, 0, stream>>>(in_w, in_wb);
  k_cvt<<<512, 256, 0, stream>>>(gate_w, gate_wb, 131072);
  k_cvt<<<512, 256, 0, stream>>>(sp_w,   sp_wb,   131072);
  k_cvt<<<512, 256, 0, stream>>>(op_w,   op_wb,   131072);
  k_cvt<<<256, 256, 0, stream>>>(out_w,  out_wb,  65536);
  k_spT<<<dim3(256,2), 256, 0, stream>>>(sp_w, sp_wTb);
  k_decay<<<512, 256, 0, stream>>>(A_log, decay);

  // pipeline
  k_in_proj<<<MTOT/64, 256, 0, stream>>>(x, in_wb, in_b, in_ln_g, in_ln_b, h_g);
  k_layers<<<NSEQ, 512, 0, stream>>>(h_g, gate_wb, sp_wb, sp_wTb, op_wb,
      ln_g, ln_b, gate_b, sp_b, decay, Dp, op_b);
  k_out<<<NSEQ/64, 256, 0, stream>>>(h_g, out_wb, out_b, out_ln_g, out_ln_b, (float*)d_out);
}